// Round 6
// baseline (278.348 us; speedup 1.0000x reference)
//
#include <hip/hip_runtime.h>
#include <hip/hip_bf16.h>
#include <type_traits>

typedef unsigned short u16;
typedef __attribute__((ext_vector_type(8))) short  s16x8;
typedef __attribute__((ext_vector_type(4))) short  s16x4;
typedef __attribute__((ext_vector_type(8))) __bf16 b16x8;
typedef __attribute__((ext_vector_type(4))) float  f32x4;

#define S_LEN 4096
#define NB    4
#define EMB   1024
#define NH    16
#define HD    64
#define NROWS (NB * S_LEN)   // 16384
#define KDIM  1024
#define BHSTRIDE (S_LEN * HD)   // 262144 u16 per (b,h) for Kp / Vt

static __device__ __forceinline__ u16 f2b(float f) {
  __hip_bfloat16 h = __float2bfloat16(f);
  return __builtin_bit_cast(u16, h);
}

// ---- MFMA shim ----
template <typename T, typename = void>
struct mfma_takes : std::false_type {};
template <typename T>
struct mfma_takes<T, std::void_t<decltype(__builtin_amdgcn_mfma_f32_16x16x32_bf16(
    std::declval<T>(), std::declval<T>(), std::declval<f32x4>(), 0, 0, 0))>> : std::true_type {};

template <typename AB>
static __device__ __forceinline__ f32x4 mfma_any(AB a, AB b, f32x4 c) {
  return __builtin_amdgcn_mfma_f32_16x16x32_bf16(a, b, c, 0, 0, 0);
}

template <typename S8 = s16x8, typename B8 = b16x8>
static __device__ __forceinline__ f32x4 MFMA_BF16(s16x8 a, s16x8 b, f32x4 c) {
  if constexpr (mfma_takes<S8>::value)
    return mfma_any<S8>(__builtin_bit_cast(S8, a), __builtin_bit_cast(S8, b), c);
  else
    return mfma_any<B8>(__builtin_bit_cast(B8, a), __builtin_bit_cast(B8, b), c);
}

static __device__ __forceinline__ void gld_lds16(const void* g, void* l) {
  __builtin_amdgcn_global_load_lds((const __attribute__((address_space(1))) void*)g,
                                   (__attribute__((address_space(3))) void*)l, 16, 0, 0);
}

// ---------------- fp32 -> bf16 conversion (x) ----------------
__global__ __launch_bounds__(256) void cvt_x_kernel(const float* __restrict__ in,
                                                    u16* __restrict__ out) {
  long i = ((long)blockIdx.x * 256 + threadIdx.x) * 8;
  float4 a = *(const float4*)(in + i);
  float4 b = *(const float4*)(in + i + 4);
  s16x8 o;
  o[0] = (short)f2b(a.x); o[1] = (short)f2b(a.y); o[2] = (short)f2b(a.z); o[3] = (short)f2b(a.w);
  o[4] = (short)f2b(b.x); o[5] = (short)f2b(b.y); o[6] = (short)f2b(b.z); o[7] = (short)f2b(b.w);
  *(s16x8*)(out + i) = o;
}

// ---------------- transpose + convert 4 x W, fused ----------------
__global__ __launch_bounds__(256) void transpose_cvt4_kernel(
    const float* __restrict__ W0, const float* __restrict__ W1,
    const float* __restrict__ W2, const float* __restrict__ W3,
    u16* __restrict__ D0, u16* __restrict__ D1, u16* __restrict__ D2, u16* __restrict__ D3) {
  __shared__ float tile[32][33];
  const float* W; u16* D;
  switch (blockIdx.z) {
    case 0:  W = W0; D = D0; break;
    case 1:  W = W1; D = D1; break;
    case 2:  W = W2; D = D2; break;
    default: W = W3; D = D3; break;
  }
  int n0 = blockIdx.x * 32, k0 = blockIdx.y * 32;
  int tx = threadIdx.x & 31, ty = threadIdx.x >> 5;
#pragma unroll
  for (int i = ty; i < 32; i += 8)
    tile[i][tx] = W[(long)(k0 + i) * EMB + n0 + tx];
  __syncthreads();
#pragma unroll
  for (int i = ty; i < 32; i += 8)
    D[(long)(n0 + i) * EMB + k0 + tx] = f2b(tile[tx][i]);
}

// ================= 256x256 8-phase GEMM, register-skewed pipeline =================
// Phase i issues ds_reads for phase i+1's quadrant and runs MFMA on regs read at i-1.
// Wait before MFMA: counted lgkmcnt(#reads issued THIS phase) -> prev phase's reads done.
// Slot map (stage @ phase -> slot, kcol):  i0:SA11,k1+32  i1:SB11,k1+32  i2:SA00,k2
//   i3:SB00,k2  i4:SA01,k2+32  i5:SB01,k2+32  i6:SA10,k3  i7:SB10,k3
// Read map (reads @ phase-top, for next phase): i0:SA00  i1:SA01+SB01  i2:SA01  i3:SA10+SB10
//   i4:SA10  i5:SA11+SB11  i6:SA11  i7:SA00+SB00(next iter)
// RAW ledger (vmcnt(4) at ends of i1,i3,i5,i7; queue = 2 loads/stage):
//   i1-end drains prev-i6,prev-i7 -> covers reads i3(SA10@pi6,SB10@pi7), i4
//   i3-end drains i0,i1          -> covers reads i5(SA11@i0,SB11@i1), i6
//   i5-end drains i2,i3          -> covers reads i7(SA00@i2,SB00@i3), next-i0
//   i7-end drains i4,i5          -> covers reads next-i1/i2 (SA01@i4,SB01@i5)
// WAR ledger: stage@s vs reads@r of same slot: all gaps >= 2 phases (2+ barriers), and
//   reads@r vs stage@(r+1) touch disjoint slots (checked pairwise). Reads@r are complete
//   before the wave passes BAR2(r+1) (its lgkmcnt at r+1), i.e. before any stage@(r+2).
#define SA_(p,k) (((p)*2+(k))*8192)
#define SB_(p,k) (32768 + ((p)*2+(k))*8192)

__global__ __launch_bounds__(512, 2) void gemm8p_kernel(
    const u16* __restrict__ A, const u16* __restrict__ Bt,
    const float* __restrict__ b0, const float* __restrict__ b1, const float* __restrict__ b2,
    void* __restrict__ Cp, u16* __restrict__ Qb, u16* __restrict__ Kp, u16* __restrict__ Vt,
    int N, int out_f32) {
  __shared__ __align__(16) u16 smem[65536];   // 128 KiB
  const int tid = threadIdx.x;
  const int w = tid >> 6, lane = tid & 63;
  const int wm = w >> 2, wn = w & 3;
  const int frow = lane & 15, fg = lane >> 4;

  const int nwg = gridDim.x;
  const int bid = ((int)blockIdx.x & 7) * (nwg >> 3) + ((int)blockIdx.x >> 3);
  const int nbn = N >> 8;
  const int bm = bid / nbn, bn = bid % nbn;

  int offA[8];
#pragma unroll
  for (int j = 0; j < 8; j++) {
    int row = wm * 128 + j * 16 + frow;
    offA[j] = row * 32 + ((fg ^ ((row ^ (row >> 2)) & 3)) << 3);
  }
  int offB[4];
#pragma unroll
  for (int j = 0; j < 4; j++) {
    int row = wn * 64 + j * 16 + frow;
    offB[j] = row * 32 + ((fg ^ ((row ^ (row >> 2)) & 3)) << 3);
  }
  int srow[2], soff[2];
#pragma unroll
  for (int L = 0; L < 2; L++) {
    int lin = L * 512 + tid;
    int r = lin >> 2;
    srow[L] = r;
    soff[L] = (((lin & 3) ^ ((r ^ (r >> 2)) & 3)) << 3);
  }
  const u16* Abase = A + (long)bm * 256 * KDIM;
  const u16* Bbase = Bt + (long)bn * 256 * KDIM;

  f32x4 acc[8][4];
#pragma unroll
  for (int m = 0; m < 8; m++)
#pragma unroll
    for (int n = 0; n < 4; n++) acc[m][n] = (f32x4)0.0f;

  auto STAGE = [&](const u16* gb, int kcol, int slot) {
#pragma unroll
    for (int L = 0; L < 2; L++)
      gld_lds16(gb + (long)srow[L] * KDIM + kcol + soff[L],
                &smem[slot + (L * 512 + w * 64) * 8]);
  };

  s16x8 af[2][4], bfr[2][4];

  // ---- prologue: 6 stages; drain first tile's k0 slots; pre-read quadrant j0
  STAGE(Abase, 0,  SA_(0,0)); STAGE(Bbase, 0,  SB_(0,0));
  STAGE(Abase, 32, SA_(0,1)); STAGE(Bbase, 32, SB_(0,1));
  STAGE(Abase, 64, SA_(1,0)); STAGE(Bbase, 64, SB_(1,0));
  asm volatile("s_waitcnt vmcnt(8)" ::: "memory");
  asm volatile("s_barrier" ::: "memory");
#pragma unroll
  for (int n = 0; n < 4; n++) bfr[0][n] = *(const s16x8*)&smem[SB_(0,0) + offB[n]];
#pragma unroll
  for (int m = 0; m < 4; m++) af[0][m] = *(const s16x8*)&smem[SA_(0,0) + offA[m]];

#define PH(PN, KN, MHN, RDB, AW, BW, GB, KCOL, SLOT, VM, MHC, AU, BU, LGN)    \
  {                                                                           \
    if (RDB) {                                                                \
      _Pragma("unroll") for (int n = 0; n < 4; n++)                           \
        bfr[BW][n] = *(const s16x8*)&smem[SB_(PN, KN) + offB[n]];             \
    }                                                                         \
    _Pragma("unroll") for (int m = 0; m < 4; m++)                             \
      af[AW][m] = *(const s16x8*)&smem[SA_(PN, KN) + offA[(MHN) * 4 + m]];    \
    STAGE(GB, KCOL, SLOT);                                                    \
    asm volatile("s_barrier" ::: "memory");                                   \
    asm volatile("s_waitcnt lgkmcnt(" #LGN ")" ::: "memory");                 \
    __builtin_amdgcn_sched_barrier(0);                                        \
    __builtin_amdgcn_s_setprio(1);                                            \
    _Pragma("unroll") for (int m = 0; m < 4; m++)                             \
      _Pragma("unroll") for (int n = 0; n < 4; n++)                           \
        acc[(MHC) * 4 + m][n] =                                               \
            MFMA_BF16(af[AU][m], bfr[BU][n], acc[(MHC) * 4 + m][n]);          \
    __builtin_amdgcn_s_setprio(0);                                            \
    if (VM) asm volatile("s_waitcnt vmcnt(4)" ::: "memory");                  \
    asm volatile("s_barrier" ::: "memory");                                   \
  }

#pragma unroll 1
  for (int i = 0; i < 8; i++) {
    const int t = 2 * i;
    const int k1 = ((t + 1) & 15) * 64;
    const int k2 = ((t + 2) & 15) * 64;   // wraps harmlessly on last iter (data unused)
    const int k3 = ((t + 3) & 15) * 64;
    PH(0, 0, 1, 0, 1, 0, Abase, k1 + 32, SA_(1, 1), 0, 0, 0, 0, 4)
    PH(0, 1, 0, 1, 0, 1, Bbase, k1 + 32, SB_(1, 1), 1, 1, 1, 0, 8)
    PH(0, 1, 1, 0, 1, 0, Abase, k2,      SA_(0, 0), 0, 0, 0, 1, 4)
    PH(1, 0, 0, 1, 0, 0, Bbase, k2,      SB_(0, 0), 1, 1, 1, 1, 8)
    PH(1, 0, 1, 0, 1, 0, Abase, k2 + 32, SA_(0, 1), 0, 0, 0, 0, 4)
    PH(1, 1, 0, 1, 0, 1, Bbase, k2 + 32, SB_(0, 1), 1, 1, 1, 0, 8)
    PH(1, 1, 1, 0, 1, 0, Abase, k3,      SA_(1, 0), 0, 0, 0, 1, 4)
    PH(0, 0, 0, 1, 0, 0, Bbase, k3,      SB_(1, 0), 1, 1, 1, 1, 8)
  }
#undef PH

  asm volatile("s_waitcnt vmcnt(0) lgkmcnt(0)" ::: "memory");
  asm volatile("s_barrier" ::: "memory");

  const int Mbase = bm * 256 + wm * 128;

  if (!out_f32) {
    // ---- split writer: Q rows / K rows (per-head) / V transposed ----
    const int g = bn * 256 + wn * 64;      // wave's global col slab = one head
    const int part = g >> 10;              // 0=Q 1=K 2=V
    const int head = (g & 1023) >> 6;
    const float* bias = (part == 0) ? b0 : ((part == 1) ? b1 : b2);
    float bv[4];
#pragma unroll
    for (int n = 0; n < 4; n++) bv[n] = bias[(g & 1023) + n * 16 + frow];
    u16* buf = &smem[w * 2048];            // [32][64] swizzled, 4KB/wave
#pragma unroll
    for (int mf2 = 0; mf2 < 4; mf2++) {
#pragma unroll
      for (int half = 0; half < 2; half++) {
        const int mf = mf2 * 2 + half;
#pragma unroll
        for (int n = 0; n < 4; n++)
#pragma unroll
          for (int r = 0; r < 4; r++) {
            int row32 = half * 16 + 4 * fg + r;
            int col = n * 16 + frow;
            buf[row32 * 64 + (((col >> 3) ^ (row32 & 7)) << 3) + (col & 7)] =
                f2b(acc[mf][n][r] + bv[n]);
          }
      }
      asm volatile("s_waitcnt lgkmcnt(0)" ::: "memory");
      __builtin_amdgcn_sched_barrier(0);
      const int s0 = Mbase + mf2 * 32;
      if (part == 2) {
        // V: lane owns d=lane; gather column, store 64B along s (full sector)
        const int d = lane;
        u16 tmp[32];
#pragma unroll
        for (int r32 = 0; r32 < 32; r32++)
          tmp[r32] = buf[r32 * 64 + (((d >> 3) ^ (r32 & 7)) << 3) + (d & 7)];
        u16* dst = Vt + ((long)((s0 >> 12) * 16 + head)) * BHSTRIDE + (long)d * S_LEN + (s0 & 4095);
#pragma unroll
        for (int q = 0; q < 4; q++) {
          s16x8 pk;
#pragma unroll
          for (int j = 0; j < 8; j++) pk[j] = (short)tmp[q * 8 + j];
          *(s16x8*)(dst + q * 8) = pk;
        }
      } else {
#pragma unroll
        for (int i = 0; i < 4; i++) {
          int flat = lane + 64 * i;
          int row32 = flat >> 3, ch = flat & 7;
          s16x8 v = *(const s16x8*)&buf[row32 * 64 + ((ch ^ (row32 & 7)) << 3)];
          int s = s0 + row32;
          u16* dst = (part == 0)
              ? (Qb + (long)s * 1024 + head * 64 + ch * 8)
              : (Kp + ((long)(s >> 12) * 16 + head) * BHSTRIDE + (long)(s & 4095) * 64 + ch * 8);
          *(s16x8*)dst = v;
        }
      }
      asm volatile("s_waitcnt lgkmcnt(0)" ::: "memory");
      __builtin_amdgcn_sched_barrier(0);
    }
  } else {
    // ---- f32 writer (gemm2): swizzled pitch-64 f32 bounce ----
    float* fbuf = (float*)&smem[w * 2048];   // [16][64] f32, 4KB/wave
    const long crow0 = (long)Mbase * N + bn * 256 + wn * 64;
#pragma unroll
    for (int mf = 0; mf < 8; mf++) {
#pragma unroll
      for (int n = 0; n < 4; n++) {
        float bvv = b0[(bn * 256 + wn * 64 + n * 16 + frow) & 1023];
#pragma unroll
        for (int r = 0; r < 4; r++) {
          int row = 4 * fg + r;
          int o = 4 * n + (frow >> 2);
          fbuf[row * 64 + ((o ^ (row & 7)) << 2) + (frow & 3)] = acc[mf][n][r] + bvv;
        }
      }
      asm volatile("s_waitcnt lgkmcnt(0)" ::: "memory");
      __builtin_amdgcn_sched_barrier(0);
#pragma unroll
      for (int i = 0; i < 4; i++) {
        int flat = lane + 64 * i;
        int row = flat >> 4, oct = lane & 15;
        float4 v = *(const float4*)&fbuf[row * 64 + ((oct ^ (row & 7)) << 2)];
        *(float4*)((float*)Cp + crow0 + (long)(mf * 16 + row) * N + oct * 4) = v;
      }
      asm volatile("s_waitcnt lgkmcnt(0)" ::: "memory");
      __builtin_amdgcn_sched_barrier(0);
    }
  }
}

// ---------------- local attention (DMA staging, double-buffered) ----------------
#define QBLK 128

__global__ __launch_bounds__(256) void attn_kernel(const u16* __restrict__ Qb,
                                                   const u16* __restrict__ Kp,
                                                   const u16* __restrict__ Vt,
                                                   u16* __restrict__ Oa) {
  __shared__ __align__(16) u16 smem[16384];   // lK[2][64][64] + lV[2][64][64] = 32KB

  const int tid = threadIdx.x;
  const int w = tid >> 6, lane = tid & 63;
  const int frow = lane & 15, fg = lane >> 4;

  const int nq = S_LEN / QBLK;             // 32
  int bid = (int)blockIdx.x;
  bid = (bid & 7) * ((NB * NH * nq) >> 3) + (bid >> 3);   // XCD swizzle
  const int b = bid / (NH * nq);
  const int rem = bid % (NH * nq);
  const int h = rem / nq;
  const int qt = rem % nq;
  const int q0 = qt * QBLK;
  const int qw0 = q0 + 32 * w;

  const u16* Kpb = Kp + (long)(b * NH + h) * BHSTRIDE;
  const u16* Vtb = Vt + (long)(b * NH + h) * BHSTRIDE;

  s16x8 qf[2][2];
#pragma unroll
  for (int m = 0; m < 2; m++)
#pragma unroll
    for (int kk = 0; kk < 2; kk++)
      qf[m][kk] = *(const s16x8*)(Qb + (long)(b * S_LEN + qw0 + 16 * m + frow) * 1024 +
                                  h * 64 + kk * 32 + 8 * fg);

  f32x4 acc[2][4];
#pragma unroll
  for (int m = 0; m < 2; m++)
#pragma unroll
    for (int n = 0; n < 4; n++) acc[m][n] = (f32x4)0.0f;
  float mrow[2] = {-1e30f, -1e30f};
  float lrow[2] = {0.f, 0.f};

  const int r8 = lane >> 3;
  const int cs = ((lane & 7) ^ r8) << 3;     // swizzled source chunk (u16 units)

  auto STAGE = [&](int kvb, int bufi) {
#pragma unroll
    for (int pass = 0; pass < 2; pass++) {
      int rbase = pass * 32 + w * 8;
      gld_lds16(Kpb + (long)(kvb + rbase + r8) * 64 + cs, &smem[bufi * 4096 + rbase * 64]);
      gld_lds16(Vtb + (long)(rbase + r8) * S_LEN + kvb + cs, &smem[8192 + bufi * 4096 + rbase * 64]);
    }
  };

  const int tlo = (q0 == 0) ? 2 : 0;
  const int thi = (q0 == S_LEN - QBLK) ? 3 : 5;

  STAGE(q0 - 128 + 64 * tlo, 0);

#pragma unroll 1
  for (int t = tlo; t <= thi; t++) {
    const int cur = (t - tlo) & 1;
    const int kvb = q0 - 128 + 64 * t;
    if (t < thi) {
      STAGE(kvb + 64, cur ^ 1);
      asm volatile("s_waitcnt vmcnt(4)" ::: "memory");
    } else {
      asm volatile("s_waitcnt vmcnt(0)" ::: "memory");
    }
    asm volatile("s_barrier" ::: "memory");

    const bool active = (kvb + 63 >= qw0 - 128) && (kvb <= qw0 + 159);
    if (active) {
      const u16* lK = &smem[cur * 4096];
      const u16* lV = &smem[8192 + cur * 4096];
      f32x4 sfr[2][4];
#pragma unroll
      for (int m = 0; m < 2; m++)
#pragma unroll
        for (int n = 0; n < 4; n++) sfr[m][n] = (f32x4)0.0f;
#pragma unroll
      for (int kk = 0; kk < 2; kk++) {
        s16x8 kb[4];
#pragma unroll
        for (int n = 0; n < 4; n++)
          kb[n] = *(const s16x8*)&lK[(16 * n + frow) * 64 + (((fg + 4 * kk) ^ (frow & 7)) << 3)];
#pragma unroll
        for (int m = 0; m < 2; m++)
#pragma unroll
          for (int n = 0; n < 4; n++)
            sfr[m][n] = MFMA_BF16(kb[n], qf[m][kk], sfr[m][n]);
      }
#pragma unroll
      for (int m = 0; m < 2; m++) {
        const int q = qw0 + 16 * m + frow;
        float p[4][4];
        float tmax = -1e30f;
#pragma unroll
        for (int n = 0; n < 4; n++)
#pragma unroll
          for (int r = 0; r < 4; r++) {
            int kv = kvb + 16 * n + 4 * fg + r;
            bool valid = (kv >= q - 128) && (kv <= q + 128) && (kv >= 0) && (kv < S_LEN);
            float xv = valid ? sfr[m][n][r] * 0.125f : -1e30f;
            p[n][r] = xv;
            tmax = fmaxf(tmax, xv);
          }
        tmax = fmaxf(tmax, __shfl_xor(tmax, 16));
        tmax = fmaxf(tmax, __shfl_xor(tmax, 32));
        float mold = mrow[m];
        float mnew = fmaxf(mold, tmax);
        float al = __expf(mold - mnew);
        mrow[m] = mnew;
        float ps = 0.f;
#pragma unroll
        for (int n = 0; n < 4; n++)
#pragma unroll
          for (int r = 0; r < 4; r++) {
            float e = (p[n][r] > -1e29f) ? __expf(p[n][r] - mnew) : 0.f;
            p[n][r] = e;
            ps += e;
          }
        ps += __shfl_xor(ps, 16);
        ps += __shfl_xor(ps, 32);
        lrow[m] = lrow[m] * al + ps;
        float a4[4];
#pragma unroll
        for (int r = 0; r < 4; r++) a4[r] = __shfl(al, 20 * fg + r);
#pragma unroll
        for (int nd = 0; nd < 4; nd++)
#pragma unroll
          for (int r = 0; r < 4; r++) acc[m][nd][r] *= a4[r];
#pragma unroll
        for (int kt = 0; kt < 2; kt++) {
          s16x8 pa;
#pragma unroll
          for (int j = 0; j < 8; j++)
            pa[j] = (short)f2b(p[2 * kt + (j >> 2)][j & 3]);
#pragma unroll
          for (int nd = 0; nd < 4; nd++) {
            const int d = 16 * nd + frow;
            const int key = frow & 7;
            const int olo = (4 * kt + (fg >> 1)) ^ key;
            const int ohi = (4 * kt + 2 + (fg >> 1)) ^ key;
            s16x4 lo = *(const s16x4*)&lV[d * 64 + olo * 8 + (fg & 1) * 4];
            s16x4 hi = *(const s16x4*)&lV[d * 64 + ohi * 8 + (fg & 1) * 4];
            s16x8 vb;
            vb[0] = lo[0]; vb[1] = lo[1]; vb[2] = lo[2]; vb[3] = lo[3];
            vb[4] = hi[0]; vb[5] = hi[1]; vb[6] = hi[2]; vb[7] = hi[3];
            acc[m][nd] = MFMA_BF16(pa, vb, acc[m][nd]);
          }
        }
      }
    }
    asm volatile("s_barrier" ::: "memory");
  }

  float i4[2][4];
#pragma unroll
  for (int m = 0; m < 2; m++) {
    float inv = 1.0f / lrow[m];
#pragma unroll
    for (int r = 0; r < 4; r++) i4[m][r] = __shfl(inv, 20 * fg + r);
  }
  u16* bb = &smem[w * 2048];   // [32][64] swizzled
#pragma unroll
  for (int m = 0; m < 2; m++)
#pragma unroll
    for (int nd = 0; nd < 4; nd++)
#pragma unroll
      for (int r = 0; r < 4; r++) {
        int row32 = 16 * m + 4 * fg + r;
        int col = 16 * nd + frow;
        bb[row32 * 64 + (((col >> 3) ^ (row32 & 7)) << 3) + (col & 7)] =
            f2b(acc[m][nd][r] * i4[m][r]);
      }
  asm volatile("s_waitcnt lgkmcnt(0)" ::: "memory");
  __builtin_amdgcn_sched_barrier(0);
  u16* Ob = Oa + ((long)(b * S_LEN + qw0)) * EMB + h * HD;
#pragma unroll
  for (int i = 0; i < 4; i++) {
    int flat = lane + 64 * i;
    int row32 = flat >> 3, ch = flat & 7;
    s16x8 v = *(const s16x8*)&bb[row32 * 64 + ((ch ^ (row32 & 7)) << 3)];
    *(s16x8*)(Ob + (long)row32 * EMB + ch * 8) = v;
  }
}

extern "C" void kernel_launch(void* const* d_in, const int* in_sizes, int n_in,
                              void* d_out, int out_size, void* d_ws, size_t ws_size,
                              hipStream_t stream) {
  const float* x  = (const float*)d_in[0];
  const float* Wq = (const float*)d_in[1];
  const float* bq = (const float*)d_in[2];
  const float* Wk = (const float*)d_in[3];
  const float* bk = (const float*)d_in[4];
  const float* Wv = (const float*)d_in[5];
  const float* bv = (const float*)d_in[6];
  const float* Wo = (const float*)d_in[7];
  const float* bo = (const float*)d_in[8];

  char* ws = (char*)d_ws;
  u16* xb   = (u16*)ws;  ws += (size_t)NROWS * EMB * 2;        // 32 MB
  u16* Wt   = (u16*)ws;  ws += (size_t)3 * EMB * EMB * 2;      // 6 MB
  u16* Wot  = (u16*)ws;  ws += (size_t)EMB * EMB * 2;          // 2 MB
  u16* Qbuf = (u16*)ws;  ws += (size_t)NROWS * EMB * 2;        // 32 MB
  u16* Kpb  = (u16*)ws;  ws += (size_t)NB * NH * BHSTRIDE * 2; // 32 MB
  u16* Vtb  = (u16*)ws;  ws += (size_t)NB * NH * BHSTRIDE * 2; // 32 MB
  u16* Oab  = (u16*)ws;  ws += (size_t)NROWS * EMB * 2;        // 32 MB

  cvt_x_kernel<<<(NROWS * EMB) / (256 * 8), 256, 0, stream>>>(x, xb);

  dim3 tg(EMB / 32, EMB / 32, 4);
  transpose_cvt4_kernel<<<tg, 256, 0, stream>>>(
      Wq, Wk, Wv, Wo, Wt, Wt + (size_t)EMB * EMB, Wt + (size_t)2 * EMB * EMB, Wot);

  gemm8p_kernel<<<(NROWS / 256) * (3 * EMB / 256), 512, 0, stream>>>(
      xb, Wt, bq, bk, bv, nullptr, Qbuf, Kpb, Vtb, 3 * EMB, 0);

  attn_kernel<<<NB * NH * (S_LEN / QBLK), 256, 0, stream>>>(Qbuf, Kpb, Vtb, Oab);

  gemm8p_kernel<<<(NROWS / 256) * (EMB / 256), 512, 0, stream>>>(
      Oab, Wot, bo, bo, bo, d_out, nullptr, nullptr, nullptr, EMB, 1);
}

// Round 7
// 252.053 us; speedup vs baseline: 1.1043x; 1.1043x over previous
//
#include <hip/hip_runtime.h>
#include <hip/hip_bf16.h>
#include <type_traits>

typedef unsigned short u16;
typedef __attribute__((ext_vector_type(8))) short  s16x8;
typedef __attribute__((ext_vector_type(4))) short  s16x4;
typedef __attribute__((ext_vector_type(8))) __bf16 b16x8;
typedef __attribute__((ext_vector_type(4))) float  f32x4;

#define S_LEN 4096
#define NB    4
#define EMB   1024
#define NH    16
#define HD    64
#define NROWS (NB * S_LEN)   // 16384
#define KDIM  1024
#define BHSTRIDE (S_LEN * HD)   // 262144 u16 per (b,h) for Kp / Vt

static __device__ __forceinline__ u16 f2b(float f) {
  __hip_bfloat16 h = __float2bfloat16(f);
  return __builtin_bit_cast(u16, h);
}

// ---- MFMA shim ----
template <typename T, typename = void>
struct mfma_takes : std::false_type {};
template <typename T>
struct mfma_takes<T, std::void_t<decltype(__builtin_amdgcn_mfma_f32_16x16x32_bf16(
    std::declval<T>(), std::declval<T>(), std::declval<f32x4>(), 0, 0, 0))>> : std::true_type {};

template <typename AB>
static __device__ __forceinline__ f32x4 mfma_any(AB a, AB b, f32x4 c) {
  return __builtin_amdgcn_mfma_f32_16x16x32_bf16(a, b, c, 0, 0, 0);
}

template <typename S8 = s16x8, typename B8 = b16x8>
static __device__ __forceinline__ f32x4 MFMA_BF16(s16x8 a, s16x8 b, f32x4 c) {
  if constexpr (mfma_takes<S8>::value)
    return mfma_any<S8>(__builtin_bit_cast(S8, a), __builtin_bit_cast(S8, b), c);
  else
    return mfma_any<B8>(__builtin_bit_cast(B8, a), __builtin_bit_cast(B8, b), c);
}

static __device__ __forceinline__ void gld_lds16(const void* g, void* l) {
  __builtin_amdgcn_global_load_lds((const __attribute__((address_space(1))) void*)g,
                                   (__attribute__((address_space(3))) void*)l, 16, 0, 0);
}

// ---------------- fp32 -> bf16 conversion (x) ----------------
__global__ __launch_bounds__(256) void cvt_x_kernel(const float* __restrict__ in,
                                                    u16* __restrict__ out) {
  long i = ((long)blockIdx.x * 256 + threadIdx.x) * 8;
  float4 a = *(const float4*)(in + i);
  float4 b = *(const float4*)(in + i + 4);
  s16x8 o;
  o[0] = (short)f2b(a.x); o[1] = (short)f2b(a.y); o[2] = (short)f2b(a.z); o[3] = (short)f2b(a.w);
  o[4] = (short)f2b(b.x); o[5] = (short)f2b(b.y); o[6] = (short)f2b(b.z); o[7] = (short)f2b(b.w);
  *(s16x8*)(out + i) = o;
}

// ---------------- transpose + convert 4 x W, fused ----------------
__global__ __launch_bounds__(256) void transpose_cvt4_kernel(
    const float* __restrict__ W0, const float* __restrict__ W1,
    const float* __restrict__ W2, const float* __restrict__ W3,
    u16* __restrict__ D0, u16* __restrict__ D1, u16* __restrict__ D2, u16* __restrict__ D3) {
  __shared__ float tile[32][33];
  const float* W; u16* D;
  switch (blockIdx.z) {
    case 0:  W = W0; D = D0; break;
    case 1:  W = W1; D = D1; break;
    case 2:  W = W2; D = D2; break;
    default: W = W3; D = D3; break;
  }
  int n0 = blockIdx.x * 32, k0 = blockIdx.y * 32;
  int tx = threadIdx.x & 31, ty = threadIdx.x >> 5;
#pragma unroll
  for (int i = ty; i < 32; i += 8)
    tile[i][tx] = W[(long)(k0 + i) * EMB + n0 + tx];
  __syncthreads();
#pragma unroll
  for (int i = ty; i < 32; i += 8)
    D[(long)(n0 + i) * EMB + k0 + tx] = f2b(tile[tx][i]);
}

// ================= 256x256 8-phase GEMM (r3 choreography restored) =================
// Per phase: {ds_read this phase's fragments; STAGE one slot; barrier; lgkmcnt(0);
//   setprio(1); 16 MFMA; setprio(0); [vmcnt(8) on even phases]; barrier}.
// vmcnt(8) only ever waits on loads issued >= 2 phases earlier (r3-verified ledger):
//   prologue 12 loads, vmcnt(8) drains SA00+SB00; P2-end drains SA01+SB01 (for P3/P4);
//   P4-end drains SA10+SB10 (for P5/P6); P6-end drains P1/P2 stages (for P7/P8);
//   P8-end drains P3/P4 stages (for next P1/P2). Never waits on <2-phase-old loads.
#define SA_(p,k) (((p)*2+(k))*8192)
#define SB_(p,k) (32768 + ((p)*2+(k))*8192)

__global__ __launch_bounds__(512, 2) void gemm8p_kernel(
    const u16* __restrict__ A, const u16* __restrict__ Bt,
    const float* __restrict__ b0, const float* __restrict__ b1, const float* __restrict__ b2,
    void* __restrict__ Cp, u16* __restrict__ Qb, u16* __restrict__ Kp, u16* __restrict__ Vt,
    int N, int out_f32) {
  __shared__ __align__(16) u16 smem[65536];   // 128 KiB
  const int tid = threadIdx.x;
  const int w = tid >> 6, lane = tid & 63;
  const int wm = w >> 2, wn = w & 3;
  const int frow = lane & 15, fg = lane >> 4;

  const int nwg = gridDim.x;
  const int bid = ((int)blockIdx.x & 7) * (nwg >> 3) + ((int)blockIdx.x >> 3);
  const int nbn = N >> 8;
  const int bm = bid / nbn, bn = bid % nbn;

  int offA[8];
#pragma unroll
  for (int j = 0; j < 8; j++) {
    int row = wm * 128 + j * 16 + frow;
    offA[j] = row * 32 + ((fg ^ ((row ^ (row >> 2)) & 3)) << 3);
  }
  int offB[4];
#pragma unroll
  for (int j = 0; j < 4; j++) {
    int row = wn * 64 + j * 16 + frow;
    offB[j] = row * 32 + ((fg ^ ((row ^ (row >> 2)) & 3)) << 3);
  }
  int srow[2], soff[2];
#pragma unroll
  for (int L = 0; L < 2; L++) {
    int lin = L * 512 + tid;
    int r = lin >> 2;
    srow[L] = r;
    soff[L] = (((lin & 3) ^ ((r ^ (r >> 2)) & 3)) << 3);
  }
  const u16* Abase = A + (long)bm * 256 * KDIM;
  const u16* Bbase = Bt + (long)bn * 256 * KDIM;

  f32x4 acc[8][4];
#pragma unroll
  for (int m = 0; m < 8; m++)
#pragma unroll
    for (int n = 0; n < 4; n++) acc[m][n] = (f32x4)0.0f;

  auto STAGE = [&](const u16* gb, int kcol, int slot) {
#pragma unroll
    for (int L = 0; L < 2; L++)
      gld_lds16(gb + (long)srow[L] * KDIM + kcol + soff[L],
                &smem[slot + (L * 512 + w * 64) * 8]);
  };

  s16x8 af[4], bf[4];

  STAGE(Abase, 0,  SA_(0,0)); STAGE(Bbase, 0,  SB_(0,0));
  STAGE(Abase, 32, SA_(0,1)); STAGE(Bbase, 32, SB_(0,1));
  STAGE(Abase, 64, SA_(1,0)); STAGE(Bbase, 64, SB_(1,0));
  asm volatile("s_waitcnt vmcnt(8)" ::: "memory");
  asm volatile("s_barrier" ::: "memory");

#define PHASE(p, k, mh, RDB, GB, KCOL, SLOT, DOVM)                            \
  {                                                                           \
    if (RDB) {                                                                \
      _Pragma("unroll") for (int n = 0; n < 4; n++)                           \
        bf[n] = *(const s16x8*)&smem[SB_(p, k) + offB[n]];                    \
    }                                                                         \
    _Pragma("unroll") for (int m = 0; m < 4; m++)                             \
      af[m] = *(const s16x8*)&smem[SA_(p, k) + offA[(mh) * 4 + m]];           \
    STAGE(GB, KCOL, SLOT);                                                    \
    asm volatile("s_barrier" ::: "memory");                                   \
    asm volatile("s_waitcnt lgkmcnt(0)" ::: "memory");                        \
    __builtin_amdgcn_sched_barrier(0);                                        \
    __builtin_amdgcn_s_setprio(1);                                            \
    _Pragma("unroll") for (int m = 0; m < 4; m++)                             \
      _Pragma("unroll") for (int n = 0; n < 4; n++)                           \
        acc[(mh) * 4 + m][n] = MFMA_BF16(af[m], bf[n], acc[(mh) * 4 + m][n]); \
    __builtin_amdgcn_s_setprio(0);                                            \
    if (DOVM) asm volatile("s_waitcnt vmcnt(8)" ::: "memory");                \
    asm volatile("s_barrier" ::: "memory");                                   \
  }

#pragma unroll 1
  for (int i = 0; i < 8; i++) {
    const int t = 2 * i;
    const int k1 = ((t + 1) & 15) * 64;
    const int k2 = ((t + 2) & 15) * 64;   // wraps harmlessly on last iter (data unused)
    const int k3 = ((t + 3) & 15) * 64;
    PHASE(0, 0, 0, 1, Abase, k1 + 32, SA_(1, 1), 0)
    PHASE(0, 0, 1, 0, Bbase, k1 + 32, SB_(1, 1), 1)
    PHASE(0, 1, 0, 1, Abase, k2,      SA_(0, 0), 0)
    PHASE(0, 1, 1, 0, Bbase, k2,      SB_(0, 0), 1)
    PHASE(1, 0, 0, 1, Abase, k2 + 32, SA_(0, 1), 0)
    PHASE(1, 0, 1, 0, Bbase, k2 + 32, SB_(0, 1), 1)
    PHASE(1, 1, 0, 1, Abase, k3,      SA_(1, 0), 0)
    PHASE(1, 1, 1, 0, Bbase, k3,      SB_(1, 0), 1)
  }
#undef PHASE

  asm volatile("s_waitcnt vmcnt(0) lgkmcnt(0)" ::: "memory");
  asm volatile("s_barrier" ::: "memory");

  const int Mbase = bm * 256 + wm * 128;

  if (!out_f32) {
    // ---- split writer: Q rows / K rows (per-head) / V transposed ----
    const int g = bn * 256 + wn * 64;      // wave's global col slab = one head
    const int part = g >> 10;              // 0=Q 1=K 2=V
    const int head = (g & 1023) >> 6;
    const float* bias = (part == 0) ? b0 : ((part == 1) ? b1 : b2);
    float bv[4];
#pragma unroll
    for (int n = 0; n < 4; n++) bv[n] = bias[(g & 1023) + n * 16 + frow];
    u16* buf = &smem[w * 2048];            // [32][64] swizzled, 4KB/wave
#pragma unroll
    for (int mf2 = 0; mf2 < 4; mf2++) {
#pragma unroll
      for (int half = 0; half < 2; half++) {
        const int mf = mf2 * 2 + half;
#pragma unroll
        for (int n = 0; n < 4; n++)
#pragma unroll
          for (int r = 0; r < 4; r++) {
            int row32 = half * 16 + 4 * fg + r;
            int col = n * 16 + frow;
            buf[row32 * 64 + (((col >> 3) ^ (row32 & 7)) << 3) + (col & 7)] =
                f2b(acc[mf][n][r] + bv[n]);
          }
      }
      asm volatile("s_waitcnt lgkmcnt(0)" ::: "memory");
      __builtin_amdgcn_sched_barrier(0);
      const int s0 = Mbase + mf2 * 32;
      if (part == 2) {
        // V: lane owns d=lane; gather column, store 64B along s (full sector)
        const int d = lane;
        u16 tmp[32];
#pragma unroll
        for (int r32 = 0; r32 < 32; r32++)
          tmp[r32] = buf[r32 * 64 + (((d >> 3) ^ (r32 & 7)) << 3) + (d & 7)];
        u16* dst = Vt + ((long)((s0 >> 12) * 16 + head)) * BHSTRIDE + (long)d * S_LEN + (s0 & 4095);
#pragma unroll
        for (int q = 0; q < 4; q++) {
          s16x8 pk;
#pragma unroll
          for (int j = 0; j < 8; j++) pk[j] = (short)tmp[q * 8 + j];
          *(s16x8*)(dst + q * 8) = pk;
        }
      } else {
#pragma unroll
        for (int i = 0; i < 4; i++) {
          int flat = lane + 64 * i;
          int row32 = flat >> 3, ch = flat & 7;
          s16x8 v = *(const s16x8*)&buf[row32 * 64 + ((ch ^ (row32 & 7)) << 3)];
          int s = s0 + row32;
          u16* dst = (part == 0)
              ? (Qb + (long)s * 1024 + head * 64 + ch * 8)
              : (Kp + ((long)(s >> 12) * 16 + head) * BHSTRIDE + (long)(s & 4095) * 64 + ch * 8);
          *(s16x8*)dst = v;
        }
      }
      asm volatile("s_waitcnt lgkmcnt(0)" ::: "memory");
      __builtin_amdgcn_sched_barrier(0);
    }
  } else {
    // ---- f32 writer (gemm2): swizzled pitch-64 f32 bounce ----
    float* fbuf = (float*)&smem[w * 2048];   // [16][64] f32, 4KB/wave
    const long crow0 = (long)Mbase * N + bn * 256 + wn * 64;
#pragma unroll
    for (int mf = 0; mf < 8; mf++) {
#pragma unroll
      for (int n = 0; n < 4; n++) {
        float bvv = b0[(bn * 256 + wn * 64 + n * 16 + frow) & 1023];
#pragma unroll
        for (int r = 0; r < 4; r++) {
          int row = 4 * fg + r;
          int o = 4 * n + (frow >> 2);
          fbuf[row * 64 + ((o ^ (row & 7)) << 2) + (frow & 3)] = acc[mf][n][r] + bvv;
        }
      }
      asm volatile("s_waitcnt lgkmcnt(0)" ::: "memory");
      __builtin_amdgcn_sched_barrier(0);
#pragma unroll
      for (int i = 0; i < 4; i++) {
        int flat = lane + 64 * i;
        int row = flat >> 4, oct = lane & 15;
        float4 v = *(const float4*)&fbuf[row * 64 + ((oct ^ (row & 7)) << 2)];
        *(float4*)((float*)Cp + crow0 + (long)(mf * 16 + row) * N + oct * 4) = v;
      }
      asm volatile("s_waitcnt lgkmcnt(0)" ::: "memory");
      __builtin_amdgcn_sched_barrier(0);
    }
  }
}

// ---------------- local attention (DMA staging, double-buffered) ----------------
// Masking: tile clamping (tlo/thi) guarantees kv in [0,S) -> only window check needed:
//   valid <=> (unsigned)(kv - q + 128) <= 256, one add + one cmp.
// V LDS reads hoisted out of the m-loop (identical for m=0/1): 16 ds_read_b64/tile.
#define QBLK 128

__global__ __launch_bounds__(256) void attn_kernel(const u16* __restrict__ Qb,
                                                   const u16* __restrict__ Kp,
                                                   const u16* __restrict__ Vt,
                                                   u16* __restrict__ Oa) {
  __shared__ __align__(16) u16 smem[16384];   // lK[2][64][64] + lV[2][64][64] = 32KB

  const int tid = threadIdx.x;
  const int w = tid >> 6, lane = tid & 63;
  const int frow = lane & 15, fg = lane >> 4;

  const int nq = S_LEN / QBLK;             // 32
  int bid = (int)blockIdx.x;
  bid = (bid & 7) * ((NB * NH * nq) >> 3) + (bid >> 3);   // XCD swizzle
  const int b = bid / (NH * nq);
  const int rem = bid % (NH * nq);
  const int h = rem / nq;
  const int qt = rem % nq;
  const int q0 = qt * QBLK;
  const int qw0 = q0 + 32 * w;

  const u16* Kpb = Kp + (long)(b * NH + h) * BHSTRIDE;
  const u16* Vtb = Vt + (long)(b * NH + h) * BHSTRIDE;

  s16x8 qf[2][2];
#pragma unroll
  for (int m = 0; m < 2; m++)
#pragma unroll
    for (int kk = 0; kk < 2; kk++)
      qf[m][kk] = *(const s16x8*)(Qb + (long)(b * S_LEN + qw0 + 16 * m + frow) * 1024 +
                                  h * 64 + kk * 32 + 8 * fg);

  f32x4 acc[2][4];
#pragma unroll
  for (int m = 0; m < 2; m++)
#pragma unroll
    for (int n = 0; n < 4; n++) acc[m][n] = (f32x4)0.0f;
  float mrow[2] = {-1e30f, -1e30f};
  float lrow[2] = {0.f, 0.f};

  const int r8 = lane >> 3;
  const int cs = ((lane & 7) ^ r8) << 3;     // swizzled source chunk (u16 units)

  auto STAGE = [&](int kvb, int bufi) {
#pragma unroll
    for (int pass = 0; pass < 2; pass++) {
      int rbase = pass * 32 + w * 8;
      gld_lds16(Kpb + (long)(kvb + rbase + r8) * 64 + cs, &smem[bufi * 4096 + rbase * 64]);
      gld_lds16(Vtb + (long)(rbase + r8) * S_LEN + kvb + cs, &smem[8192 + bufi * 4096 + rbase * 64]);
    }
  };

  const int tlo = (q0 == 0) ? 2 : 0;
  const int thi = (q0 == S_LEN - QBLK) ? 3 : 5;

  STAGE(q0 - 128 + 64 * tlo, 0);

#pragma unroll 1
  for (int t = tlo; t <= thi; t++) {
    const int cur = (t - tlo) & 1;
    const int kvb = q0 - 128 + 64 * t;
    if (t < thi) {
      STAGE(kvb + 64, cur ^ 1);
      asm volatile("s_waitcnt vmcnt(4)" ::: "memory");
    } else {
      asm volatile("s_waitcnt vmcnt(0)" ::: "memory");
    }
    asm volatile("s_barrier" ::: "memory");

    const bool active = (kvb + 63 >= qw0 - 128) && (kvb <= qw0 + 159);
    if (active) {
      const u16* lK = &smem[cur * 4096];
      const u16* lV = &smem[8192 + cur * 4096];
      // QK^T (swapped): sfr[m][n][r] = S[q = qw0+16m+frow][kv = kvb + 16n + 4fg + r]
      f32x4 sfr[2][4];
#pragma unroll
      for (int m = 0; m < 2; m++)
#pragma unroll
        for (int n = 0; n < 4; n++) sfr[m][n] = (f32x4)0.0f;
#pragma unroll
      for (int kk = 0; kk < 2; kk++) {
        s16x8 kb[4];
#pragma unroll
        for (int n = 0; n < 4; n++)
          kb[n] = *(const s16x8*)&lK[(16 * n + frow) * 64 + (((fg + 4 * kk) ^ (frow & 7)) << 3)];
#pragma unroll
        for (int m = 0; m < 2; m++)
#pragma unroll
          for (int n = 0; n < 4; n++)
            sfr[m][n] = MFMA_BF16(kb[n], qf[m][kk], sfr[m][n]);
      }
      // ---- softmax (in-place in sfr), both m, then shared-V PV ----
#pragma unroll
      for (int m = 0; m < 2; m++) {
        const int dbase = kvb - (qw0 + 16 * m + frow) + 128 + 4 * fg;  // + 16n + r
        float tmax = -1e30f;
#pragma unroll
        for (int n = 0; n < 4; n++)
#pragma unroll
          for (int r = 0; r < 4; r++) {
            bool valid = (unsigned)(dbase + 16 * n + r) <= 256u;
            float xv = valid ? sfr[m][n][r] * 0.125f : -1e30f;
            sfr[m][n][r] = xv;
            tmax = fmaxf(tmax, xv);
          }
        tmax = fmaxf(tmax, __shfl_xor(tmax, 16));
        tmax = fmaxf(tmax, __shfl_xor(tmax, 32));
        float mold = mrow[m];
        float mnew = fmaxf(mold, tmax);
        float al = __expf(mold - mnew);
        mrow[m] = mnew;
        float ps = 0.f;
#pragma unroll
        for (int n = 0; n < 4; n++)
#pragma unroll
          for (int r = 0; r < 4; r++) {
            float e = (sfr[m][n][r] > -1e29f) ? __expf(sfr[m][n][r] - mnew) : 0.f;
            sfr[m][n][r] = e;
            ps += e;
          }
        ps += __shfl_xor(ps, 16);
        ps += __shfl_xor(ps, 32);
        lrow[m] = lrow[m] * al + ps;
        float a4[4];
#pragma unroll
        for (int r = 0; r < 4; r++) a4[r] = __shfl(al, 20 * fg + r);
#pragma unroll
        for (int nd = 0; nd < 4; nd++)
#pragma unroll
          for (int r = 0; r < 4; r++) acc[m][nd][r] *= a4[r];
      }
      // pack P A-fragments for both m (k-permutation pi: k=fg*8+j <-> kv=16*(2kt+(j>>2))+4fg+(j&3))
      s16x8 pa[2][2];
#pragma unroll
      for (int m = 0; m < 2; m++)
#pragma unroll
        for (int kt = 0; kt < 2; kt++)
#pragma unroll
          for (int j = 0; j < 8; j++)
            pa[m][kt][j] = (short)f2b(sfr[m][2 * kt + (j >> 2)][j & 3]);
      // PV: V-fragments read once, shared by both m
#pragma unroll
      for (int kt = 0; kt < 2; kt++)
#pragma unroll
        for (int nd = 0; nd < 4; nd++) {
          const int d = 16 * nd + frow;
          const int key = frow & 7;
          const int olo = (4 * kt + (fg >> 1)) ^ key;
          const int ohi = (4 * kt + 2 + (fg >> 1)) ^ key;
          s16x4 lo = *(const s16x4*)&lV[d * 64 + olo * 8 + (fg & 1) * 4];
          s16x4 hi = *(const s16x4*)&lV[d * 64 + ohi * 8 + (fg & 1) * 4];
          s16x8 vb;
          vb[0] = lo[0]; vb[1] = lo[1]; vb[2] = lo[2]; vb[3] = lo[3];
          vb[4] = hi[0]; vb[5] = hi[1]; vb[6] = hi[2]; vb[7] = hi[3];
#pragma unroll
          for (int m = 0; m < 2; m++)
            acc[m][nd] = MFMA_BF16(pa[m][kt], vb, acc[m][nd]);
        }
    }
    asm volatile("s_barrier" ::: "memory");
  }

  float i4[2][4];
#pragma unroll
  for (int m = 0; m < 2; m++) {
    float inv = 1.0f / lrow[m];
#pragma unroll
    for (int r = 0; r < 4; r++) i4[m][r] = __shfl(inv, 20 * fg + r);
  }
  u16* bb = &smem[w * 2048];   // [32][64] swizzled
#pragma unroll
  for (int m = 0; m < 2; m++)
#pragma unroll
    for (int nd = 0; nd < 4; nd++)
#pragma unroll
      for (int r = 0; r < 4; r++) {
        int row32 = 16 * m + 4 * fg + r;
        int col = 16 * nd + frow;
        bb[row32 * 64 + (((col >> 3) ^ (row32 & 7)) << 3) + (col & 7)] =
            f2b(acc[m][nd][r] * i4[m][r]);
      }
  asm volatile("s_waitcnt lgkmcnt(0)" ::: "memory");
  __builtin_amdgcn_sched_barrier(0);
  u16* Ob = Oa + ((long)(b * S_LEN + qw0)) * EMB + h * HD;
#pragma unroll
  for (int i = 0; i < 4; i++) {
    int flat = lane + 64 * i;
    int row32 = flat >> 3, ch = flat & 7;
    s16x8 v = *(const s16x8*)&bb[row32 * 64 + ((ch ^ (row32 & 7)) << 3)];
    *(s16x8*)(Ob + (long)row32 * EMB + ch * 8) = v;
  }
}

extern "C" void kernel_launch(void* const* d_in, const int* in_sizes, int n_in,
                              void* d_out, int out_size, void* d_ws, size_t ws_size,
                              hipStream_t stream) {
  const float* x  = (const float*)d_in[0];
  const float* Wq = (const float*)d_in[1];
  const float* bq = (const float*)d_in[2];
  const float* Wk = (const float*)d_in[3];
  const float* bk = (const float*)d_in[4];
  const float* Wv = (const float*)d_in[5];
  const float* bv = (const float*)d_in[6];
  const float* Wo = (const float*)d_in[7];
  const float* bo = (const float*)d_in[8];

  char* ws = (char*)d_ws;
  u16* xb   = (u16*)ws;  ws += (size_t)NROWS * EMB * 2;        // 32 MB
  u16* Wt   = (u16*)ws;  ws += (size_t)3 * EMB * EMB * 2;      // 6 MB
  u16* Wot  = (u16*)ws;  ws += (size_t)EMB * EMB * 2;          // 2 MB
  u16* Qbuf = (u16*)ws;  ws += (size_t)NROWS * EMB * 2;        // 32 MB
  u16* Kpb  = (u16*)ws;  ws += (size_t)NB * NH * BHSTRIDE * 2; // 32 MB
  u16* Vtb  = (u16*)ws;  ws += (size_t)NB * NH * BHSTRIDE * 2; // 32 MB
  u16* Oab  = (u16*)ws;  ws += (size_t)NROWS * EMB * 2;        // 32 MB

  cvt_x_kernel<<<(NROWS * EMB) / (256 * 8), 256, 0, stream>>>(x, xb);

  dim3 tg(EMB / 32, EMB / 32, 4);
  transpose_cvt4_kernel<<<tg, 256, 0, stream>>>(
      Wq, Wk, Wv, Wo, Wt, Wt + (size_t)EMB * EMB, Wt + (size_t)2 * EMB * EMB, Wot);

  gemm8p_kernel<<<(NROWS / 256) * (3 * EMB / 256), 512, 0, stream>>>(
      xb, Wt, bq, bk, bv, nullptr, Qbuf, Kpb, Vtb, 3 * EMB, 0);

  attn_kernel<<<NB * NH * (S_LEN / QBLK), 256, 0, stream>>>(Qbuf, Kpb, Vtb, Oab);

  gemm8p_kernel<<<(NROWS / 256) * (EMB / 256), 512, 0, stream>>>(
      Oab, Wot, bo, bo, bo, d_out, nullptr, nullptr, nullptr, EMB, 1);
}

// Round 8
// 248.009 us; speedup vs baseline: 1.1223x; 1.0163x over previous
//
#include <hip/hip_runtime.h>
#include <hip/hip_bf16.h>
#include <type_traits>

typedef unsigned short u16;
typedef __attribute__((ext_vector_type(8))) short  s16x8;
typedef __attribute__((ext_vector_type(4))) short  s16x4;
typedef __attribute__((ext_vector_type(8))) __bf16 b16x8;
typedef __attribute__((ext_vector_type(4))) float  f32x4;

#define S_LEN 4096
#define NB    4
#define EMB   1024
#define NH    16
#define HD    64
#define NROWS (NB * S_LEN)   // 16384
#define KDIM  1024
#define BHSTRIDE (S_LEN * HD)   // 262144 u16 per (b,h) for Kp / Vt

static __device__ __forceinline__ u16 f2b(float f) {
  __hip_bfloat16 h = __float2bfloat16(f);
  return __builtin_bit_cast(u16, h);
}

// ---- MFMA shim ----
template <typename T, typename = void>
struct mfma_takes : std::false_type {};
template <typename T>
struct mfma_takes<T, std::void_t<decltype(__builtin_amdgcn_mfma_f32_16x16x32_bf16(
    std::declval<T>(), std::declval<T>(), std::declval<f32x4>(), 0, 0, 0))>> : std::true_type {};

template <typename AB>
static __device__ __forceinline__ f32x4 mfma_any(AB a, AB b, f32x4 c) {
  return __builtin_amdgcn_mfma_f32_16x16x32_bf16(a, b, c, 0, 0, 0);
}

template <typename S8 = s16x8, typename B8 = b16x8>
static __device__ __forceinline__ f32x4 MFMA_BF16(s16x8 a, s16x8 b, f32x4 c) {
  if constexpr (mfma_takes<S8>::value)
    return mfma_any<S8>(__builtin_bit_cast(S8, a), __builtin_bit_cast(S8, b), c);
  else
    return mfma_any<B8>(__builtin_bit_cast(B8, a), __builtin_bit_cast(B8, b), c);
}

static __device__ __forceinline__ void gld_lds16(const void* g, void* l) {
  __builtin_amdgcn_global_load_lds((const __attribute__((address_space(1))) void*)g,
                                   (__attribute__((address_space(3))) void*)l, 16, 0, 0);
}

// ---------------- fp32 -> bf16 conversion (x) ----------------
__global__ __launch_bounds__(256) void cvt_x_kernel(const float* __restrict__ in,
                                                    u16* __restrict__ out) {
  long i = ((long)blockIdx.x * 256 + threadIdx.x) * 8;
  float4 a = *(const float4*)(in + i);
  float4 b = *(const float4*)(in + i + 4);
  s16x8 o;
  o[0] = (short)f2b(a.x); o[1] = (short)f2b(a.y); o[2] = (short)f2b(a.z); o[3] = (short)f2b(a.w);
  o[4] = (short)f2b(b.x); o[5] = (short)f2b(b.y); o[6] = (short)f2b(b.z); o[7] = (short)f2b(b.w);
  *(s16x8*)(out + i) = o;
}

// ---------------- transpose + convert 4 x W, fused ----------------
__global__ __launch_bounds__(256) void transpose_cvt4_kernel(
    const float* __restrict__ W0, const float* __restrict__ W1,
    const float* __restrict__ W2, const float* __restrict__ W3,
    u16* __restrict__ D0, u16* __restrict__ D1, u16* __restrict__ D2, u16* __restrict__ D3) {
  __shared__ float tile[32][33];
  const float* W; u16* D;
  switch (blockIdx.z) {
    case 0:  W = W0; D = D0; break;
    case 1:  W = W1; D = D1; break;
    case 2:  W = W2; D = D2; break;
    default: W = W3; D = D3; break;
  }
  int n0 = blockIdx.x * 32, k0 = blockIdx.y * 32;
  int tx = threadIdx.x & 31, ty = threadIdx.x >> 5;
#pragma unroll
  for (int i = ty; i < 32; i += 8)
    tile[i][tx] = W[(long)(k0 + i) * EMB + n0 + tx];
  __syncthreads();
#pragma unroll
  for (int i = ty; i < 32; i += 8)
    D[(long)(n0 + i) * EMB + k0 + tx] = f2b(tile[tx][i]);
}

// ================= 256x256 8-phase GEMM (r3 choreography) =================
// vmcnt(8) at P2/P4/P6/P8 only ever waits on loads >= 2 phases old (ledger verified r3/r7).
#define SA_(p,k) (((p)*2+(k))*8192)
#define SB_(p,k) (32768 + ((p)*2+(k))*8192)

__global__ __launch_bounds__(512, 2) void gemm8p_kernel(
    const u16* __restrict__ A, const u16* __restrict__ Bt,
    const float* __restrict__ b0, const float* __restrict__ b1, const float* __restrict__ b2,
    void* __restrict__ Cp, u16* __restrict__ Qb, u16* __restrict__ Kp, u16* __restrict__ Vt,
    int N, int out_f32) {
  __shared__ __align__(16) u16 smem[65536];   // 128 KiB
  const int tid = threadIdx.x;
  const int w = tid >> 6, lane = tid & 63;
  const int wm = w >> 2, wn = w & 3;
  const int frow = lane & 15, fg = lane >> 4;

  const int nwg = gridDim.x;
  const int bid = ((int)blockIdx.x & 7) * (nwg >> 3) + ((int)blockIdx.x >> 3);
  const int nbn = N >> 8;
  const int bm = bid / nbn, bn = bid % nbn;

  int offA[8];
#pragma unroll
  for (int j = 0; j < 8; j++) {
    int row = wm * 128 + j * 16 + frow;
    offA[j] = row * 32 + ((fg ^ ((row ^ (row >> 2)) & 3)) << 3);
  }
  int offB[4];
#pragma unroll
  for (int j = 0; j < 4; j++) {
    int row = wn * 64 + j * 16 + frow;
    offB[j] = row * 32 + ((fg ^ ((row ^ (row >> 2)) & 3)) << 3);
  }
  int srow[2], soff[2];
#pragma unroll
  for (int L = 0; L < 2; L++) {
    int lin = L * 512 + tid;
    int r = lin >> 2;
    srow[L] = r;
    soff[L] = (((lin & 3) ^ ((r ^ (r >> 2)) & 3)) << 3);
  }
  const u16* Abase = A + (long)bm * 256 * KDIM;
  const u16* Bbase = Bt + (long)bn * 256 * KDIM;

  f32x4 acc[8][4];
#pragma unroll
  for (int m = 0; m < 8; m++)
#pragma unroll
    for (int n = 0; n < 4; n++) acc[m][n] = (f32x4)0.0f;

  auto STAGE = [&](const u16* gb, int kcol, int slot) {
#pragma unroll
    for (int L = 0; L < 2; L++)
      gld_lds16(gb + (long)srow[L] * KDIM + kcol + soff[L],
                &smem[slot + (L * 512 + w * 64) * 8]);
  };

  s16x8 af[4], bf[4];

  STAGE(Abase, 0,  SA_(0,0)); STAGE(Bbase, 0,  SB_(0,0));
  STAGE(Abase, 32, SA_(0,1)); STAGE(Bbase, 32, SB_(0,1));
  STAGE(Abase, 64, SA_(1,0)); STAGE(Bbase, 64, SB_(1,0));
  asm volatile("s_waitcnt vmcnt(8)" ::: "memory");
  asm volatile("s_barrier" ::: "memory");

#define PHASE(p, k, mh, RDB, GB, KCOL, SLOT, DOVM)                            \
  {                                                                           \
    if (RDB) {                                                                \
      _Pragma("unroll") for (int n = 0; n < 4; n++)                           \
        bf[n] = *(const s16x8*)&smem[SB_(p, k) + offB[n]];                    \
    }                                                                         \
    _Pragma("unroll") for (int m = 0; m < 4; m++)                             \
      af[m] = *(const s16x8*)&smem[SA_(p, k) + offA[(mh) * 4 + m]];           \
    STAGE(GB, KCOL, SLOT);                                                    \
    asm volatile("s_barrier" ::: "memory");                                   \
    asm volatile("s_waitcnt lgkmcnt(0)" ::: "memory");                        \
    __builtin_amdgcn_sched_barrier(0);                                        \
    __builtin_amdgcn_s_setprio(1);                                            \
    _Pragma("unroll") for (int m = 0; m < 4; m++)                             \
      _Pragma("unroll") for (int n = 0; n < 4; n++)                           \
        acc[(mh) * 4 + m][n] = MFMA_BF16(af[m], bf[n], acc[(mh) * 4 + m][n]); \
    __builtin_amdgcn_s_setprio(0);                                            \
    if (DOVM) asm volatile("s_waitcnt vmcnt(8)" ::: "memory");                \
    asm volatile("s_barrier" ::: "memory");                                   \
  }

#pragma unroll 1
  for (int i = 0; i < 8; i++) {
    const int t = 2 * i;
    const int k1 = ((t + 1) & 15) * 64;
    const int k2 = ((t + 2) & 15) * 64;   // wraps harmlessly on last iter (data unused)
    const int k3 = ((t + 3) & 15) * 64;
    PHASE(0, 0, 0, 1, Abase, k1 + 32, SA_(1, 1), 0)
    PHASE(0, 0, 1, 0, Bbase, k1 + 32, SB_(1, 1), 1)
    PHASE(0, 1, 0, 1, Abase, k2,      SA_(0, 0), 0)
    PHASE(0, 1, 1, 0, Bbase, k2,      SB_(0, 0), 1)
    PHASE(1, 0, 0, 1, Abase, k2 + 32, SA_(0, 1), 0)
    PHASE(1, 0, 1, 0, Bbase, k2 + 32, SB_(0, 1), 1)
    PHASE(1, 1, 0, 1, Abase, k3,      SA_(1, 0), 0)
    PHASE(1, 1, 1, 0, Bbase, k3,      SB_(1, 0), 1)
  }
#undef PHASE

  asm volatile("s_waitcnt vmcnt(0) lgkmcnt(0)" ::: "memory");
  asm volatile("s_barrier" ::: "memory");

  const int Mbase = bm * 256 + wm * 128;

  if (!out_f32) {
    const int g = bn * 256 + wn * 64;      // wave's global col slab = one head
    const int part = g >> 10;              // 0=Q 1=K 2=V
    const int head = (g & 1023) >> 6;
    const float* bias = (part == 0) ? b0 : ((part == 1) ? b1 : b2);
    float bv[4];
#pragma unroll
    for (int n = 0; n < 4; n++) bv[n] = bias[(g & 1023) + n * 16 + frow];

    if (part == 2) {
      // ---- V: direct global stores, no LDS. acc[mf][n][r] r=0..3 are 4 consecutive
      // s at d = n*16+frow -> one 8B store each; sectors complete in L2 across mf.
      const int batch = Mbase >> 12;
      const int sl0 = (Mbase & 4095) + 4 * fg;
      u16* dstb = Vt + ((long)(batch * 16 + head)) * BHSTRIDE + sl0;
#pragma unroll
      for (int n = 0; n < 4; n++) {
        const int d = n * 16 + frow;
        u16* dr = dstb + (long)d * S_LEN;
#pragma unroll
        for (int mf = 0; mf < 8; mf++) {
          s16x4 pk;
#pragma unroll
          for (int r = 0; r < 4; r++) pk[r] = (short)f2b(acc[mf][n][r] + bv[n]);
          *(s16x4*)(dr + mf * 16) = pk;
        }
      }
    } else {
      // ---- Q/K: swizzled wave-private bounce -> coalesced b128 stores
      u16* buf = &smem[w * 2048];            // [32][64] swizzled, 4KB/wave
#pragma unroll
      for (int mf2 = 0; mf2 < 4; mf2++) {
#pragma unroll
        for (int half = 0; half < 2; half++) {
          const int mf = mf2 * 2 + half;
#pragma unroll
          for (int n = 0; n < 4; n++)
#pragma unroll
            for (int r = 0; r < 4; r++) {
              int row32 = half * 16 + 4 * fg + r;
              int col = n * 16 + frow;
              buf[row32 * 64 + (((col >> 3) ^ (row32 & 7)) << 3) + (col & 7)] =
                  f2b(acc[mf][n][r] + bv[n]);
            }
        }
        asm volatile("s_waitcnt lgkmcnt(0)" ::: "memory");
        __builtin_amdgcn_sched_barrier(0);
        const int s0 = Mbase + mf2 * 32;
#pragma unroll
        for (int i = 0; i < 4; i++) {
          int flat = lane + 64 * i;
          int row32 = flat >> 3, ch = flat & 7;
          s16x8 v = *(const s16x8*)&buf[row32 * 64 + ((ch ^ (row32 & 7)) << 3)];
          int s = s0 + row32;
          u16* dst = (part == 0)
              ? (Qb + (long)s * 1024 + head * 64 + ch * 8)
              : (Kp + ((long)(s >> 12) * 16 + head) * BHSTRIDE + (long)(s & 4095) * 64 + ch * 8);
          *(s16x8*)dst = v;
        }
        asm volatile("s_waitcnt lgkmcnt(0)" ::: "memory");
        __builtin_amdgcn_sched_barrier(0);
      }
    }
  } else {
    // ---- f32 writer (gemm2): swizzled pitch-64 f32 bounce ----
    float* fbuf = (float*)&smem[w * 2048];   // [16][64] f32, 4KB/wave
    const long crow0 = (long)Mbase * N + bn * 256 + wn * 64;
#pragma unroll
    for (int mf = 0; mf < 8; mf++) {
#pragma unroll
      for (int n = 0; n < 4; n++) {
        float bvv = b0[(bn * 256 + wn * 64 + n * 16 + frow) & 1023];
#pragma unroll
        for (int r = 0; r < 4; r++) {
          int row = 4 * fg + r;
          int o = 4 * n + (frow >> 2);
          fbuf[row * 64 + ((o ^ (row & 7)) << 2) + (frow & 3)] = acc[mf][n][r] + bvv;
        }
      }
      asm volatile("s_waitcnt lgkmcnt(0)" ::: "memory");
      __builtin_amdgcn_sched_barrier(0);
#pragma unroll
      for (int i = 0; i < 4; i++) {
        int flat = lane + 64 * i;
        int row = flat >> 4, oct = lane & 15;
        float4 v = *(const float4*)&fbuf[row * 64 + ((oct ^ (row & 7)) << 2)];
        *(float4*)((float*)Cp + crow0 + (long)(mf * 16 + row) * N + oct * 4) = v;
      }
      asm volatile("s_waitcnt lgkmcnt(0)" ::: "memory");
      __builtin_amdgcn_sched_barrier(0);
    }
  }
}

// ---------------- local attention (DMA staging, double-buffered, defer-max) ----------------
#define QBLK 128

__global__ __launch_bounds__(256) void attn_kernel(const u16* __restrict__ Qb,
                                                   const u16* __restrict__ Kp,
                                                   const u16* __restrict__ Vt,
                                                   u16* __restrict__ Oa) {
  __shared__ __align__(16) u16 smem[16384];   // lK[2][64][64] + lV[2][64][64] = 32KB

  const int tid = threadIdx.x;
  const int w = tid >> 6, lane = tid & 63;
  const int frow = lane & 15, fg = lane >> 4;

  const int nq = S_LEN / QBLK;             // 32
  int bid = (int)blockIdx.x;
  bid = (bid & 7) * ((NB * NH * nq) >> 3) + (bid >> 3);   // XCD swizzle
  const int b = bid / (NH * nq);
  const int rem = bid % (NH * nq);
  const int h = rem / nq;
  const int qt = rem % nq;
  const int q0 = qt * QBLK;
  const int qw0 = q0 + 32 * w;

  const u16* Kpb = Kp + (long)(b * NH + h) * BHSTRIDE;
  const u16* Vtb = Vt + (long)(b * NH + h) * BHSTRIDE;

  s16x8 qf[2][2];
#pragma unroll
  for (int m = 0; m < 2; m++)
#pragma unroll
    for (int kk = 0; kk < 2; kk++)
      qf[m][kk] = *(const s16x8*)(Qb + (long)(b * S_LEN + qw0 + 16 * m + frow) * 1024 +
                                  h * 64 + kk * 32 + 8 * fg);

  f32x4 acc[2][4];
#pragma unroll
  for (int m = 0; m < 2; m++)
#pragma unroll
    for (int n = 0; n < 4; n++) acc[m][n] = (f32x4)0.0f;
  float mrow[2] = {-1e30f, -1e30f};
  float lrow[2] = {0.f, 0.f};

  const int r8 = lane >> 3;
  const int cs = ((lane & 7) ^ r8) << 3;     // swizzled source chunk (u16 units)

  auto STAGE = [&](int kvb, int bufi) {
#pragma unroll
    for (int pass = 0; pass < 2; pass++) {
      int rbase = pass * 32 + w * 8;
      gld_lds16(Kpb + (long)(kvb + rbase + r8) * 64 + cs, &smem[bufi * 4096 + rbase * 64]);
      gld_lds16(Vtb + (long)(rbase + r8) * S_LEN + kvb + cs, &smem[8192 + bufi * 4096 + rbase * 64]);
    }
  };

  const int tlo = (q0 == 0) ? 2 : 0;
  const int thi = (q0 == S_LEN - QBLK) ? 3 : 5;

  STAGE(q0 - 128 + 64 * tlo, 0);

#pragma unroll 1
  for (int t = tlo; t <= thi; t++) {
    const int cur = (t - tlo) & 1;
    const int kvb = q0 - 128 + 64 * t;
    if (t < thi) {
      STAGE(kvb + 64, cur ^ 1);
      asm volatile("s_waitcnt vmcnt(4)" ::: "memory");
    } else {
      asm volatile("s_waitcnt vmcnt(0)" ::: "memory");
    }
    asm volatile("s_barrier" ::: "memory");

    const bool active = (kvb + 63 >= qw0 - 128) && (kvb <= qw0 + 159);
    if (active) {
      const u16* lK = &smem[cur * 4096];
      const u16* lV = &smem[8192 + cur * 4096];
      // QK^T (swapped): sfr[m][n][r] = S[q = qw0+16m+frow][kv = kvb + 16n + 4fg + r]
      f32x4 sfr[2][4];
#pragma unroll
      for (int m = 0; m < 2; m++)
#pragma unroll
        for (int n = 0; n < 4; n++) sfr[m][n] = (f32x4)0.0f;
#pragma unroll
      for (int kk = 0; kk < 2; kk++) {
        s16x8 kb[4];
#pragma unroll
        for (int n = 0; n < 4; n++)
          kb[n] = *(const s16x8*)&lK[(16 * n + frow) * 64 + (((fg + 4 * kk) ^ (frow & 7)) << 3)];
#pragma unroll
        for (int m = 0; m < 2; m++)
#pragma unroll
          for (int n = 0; n < 4; n++)
            sfr[m][n] = MFMA_BF16(kb[n], qf[m][kk], sfr[m][n]);
      }
      // ---- softmax with defer-max (T13): rescale only if tile max grew > 8 ----
#pragma unroll
      for (int m = 0; m < 2; m++) {
        const int dbase = kvb - (qw0 + 16 * m + frow) + 128 + 4 * fg;  // + 16n + r
        float tmax = -1e30f;
#pragma unroll
        for (int n = 0; n < 4; n++)
#pragma unroll
          for (int r = 0; r < 4; r++) {
            bool valid = (unsigned)(dbase + 16 * n + r) <= 256u;
            float xv = valid ? sfr[m][n][r] * 0.125f : -1e30f;
            sfr[m][n][r] = xv;
            tmax = fmaxf(tmax, xv);
          }
        tmax = fmaxf(tmax, __shfl_xor(tmax, 16));
        tmax = fmaxf(tmax, __shfl_xor(tmax, 32));
        if (!__all(tmax - mrow[m] <= 8.0f)) {
          float mnew = fmaxf(mrow[m], tmax);
          float al = __expf(mrow[m] - mnew);
          mrow[m] = mnew;
          lrow[m] *= al;
          float a4[4];
#pragma unroll
          for (int r = 0; r < 4; r++) a4[r] = __shfl(al, 20 * fg + r);
#pragma unroll
          for (int nd = 0; nd < 4; nd++)
#pragma unroll
            for (int r = 0; r < 4; r++) acc[m][nd][r] *= a4[r];
        }
        float ps = 0.f;
#pragma unroll
        for (int n = 0; n < 4; n++)
#pragma unroll
          for (int r = 0; r < 4; r++) {
            float e = __expf(sfr[m][n][r] - mrow[m]);   // masked: exp(-huge) -> 0
            sfr[m][n][r] = e;
            ps += e;
          }
        ps += __shfl_xor(ps, 16);
        ps += __shfl_xor(ps, 32);
        lrow[m] += ps;
      }
      // pack P A-fragments for both m (k-permutation pi: k=fg*8+j <-> kv=16*(2kt+(j>>2))+4fg+(j&3))
      s16x8 pa[2][2];
#pragma unroll
      for (int m = 0; m < 2; m++)
#pragma unroll
        for (int kt = 0; kt < 2; kt++)
#pragma unroll
          for (int j = 0; j < 8; j++)
            pa[m][kt][j] = (short)f2b(sfr[m][2 * kt + (j >> 2)][j & 3]);
      // PV: V-fragments read once, shared by both m
#pragma unroll
      for (int kt = 0; kt < 2; kt++)
#pragma unroll
        for (int nd = 0; nd < 4; nd++) {
          const int d = 16 * nd + frow;
          const int key = frow & 7;
          const int olo = (4 * kt + (fg >> 1)) ^ key;
          const int ohi = (4 * kt + 2 + (fg >> 1)) ^ key;
          s16x4 lo = *(const s16x4*)&lV[d * 64 + olo * 8 + (fg & 1) * 4];
          s16x4 hi = *(const s16x4*)&lV[d * 64 + ohi * 8 + (fg & 1) * 4];
          s16x8 vb;
          vb[0] = lo[0]; vb[1] = lo[1]; vb[2] = lo[2]; vb[3] = lo[3];
          vb[4] = hi[0]; vb[5] = hi[1]; vb[6] = hi[2]; vb[7] = hi[3];
#pragma unroll
          for (int m = 0; m < 2; m++)
            acc[m][nd] = MFMA_BF16(pa[m][kt], vb, acc[m][nd]);
        }
    }
    asm volatile("s_barrier" ::: "memory");
  }

  float i4[2][4];
#pragma unroll
  for (int m = 0; m < 2; m++) {
    float inv = 1.0f / lrow[m];
#pragma unroll
    for (int r = 0; r < 4; r++) i4[m][r] = __shfl(inv, 20 * fg + r);
  }
  u16* bb = &smem[w * 2048];   // [32][64] swizzled
#pragma unroll
  for (int m = 0; m < 2; m++)
#pragma unroll
    for (int nd = 0; nd < 4; nd++)
#pragma unroll
      for (int r = 0; r < 4; r++) {
        int row32 = 16 * m + 4 * fg + r;
        int col = 16 * nd + frow;
        bb[row32 * 64 + (((col >> 3) ^ (row32 & 7)) << 3) + (col & 7)] =
            f2b(acc[m][nd][r] * i4[m][r]);
      }
  asm volatile("s_waitcnt lgkmcnt(0)" ::: "memory");
  __builtin_amdgcn_sched_barrier(0);
  u16* Ob = Oa + ((long)(b * S_LEN + qw0)) * EMB + h * HD;
#pragma unroll
  for (int i = 0; i < 4; i++) {
    int flat = lane + 64 * i;
    int row32 = flat >> 3, ch = flat & 7;
    s16x8 v = *(const s16x8*)&bb[row32 * 64 + ((ch ^ (row32 & 7)) << 3)];
    *(s16x8*)(Ob + (long)row32 * EMB + ch * 8) = v;
  }
}

extern "C" void kernel_launch(void* const* d_in, const int* in_sizes, int n_in,
                              void* d_out, int out_size, void* d_ws, size_t ws_size,
                              hipStream_t stream) {
  const float* x  = (const float*)d_in[0];
  const float* Wq = (const float*)d_in[1];
  const float* bq = (const float*)d_in[2];
  const float* Wk = (const float*)d_in[3];
  const float* bk = (const float*)d_in[4];
  const float* Wv = (const float*)d_in[5];
  const float* bv = (const float*)d_in[6];
  const float* Wo = (const float*)d_in[7];
  const float* bo = (const float*)d_in[8];

  char* ws = (char*)d_ws;
  u16* xb   = (u16*)ws;  ws += (size_t)NROWS * EMB * 2;        // 32 MB
  u16* Wt   = (u16*)ws;  ws += (size_t)3 * EMB * EMB * 2;      // 6 MB
  u16* Wot  = (u16*)ws;  ws += (size_t)EMB * EMB * 2;          // 2 MB
  u16* Qbuf = (u16*)ws;  ws += (size_t)NROWS * EMB * 2;        // 32 MB
  u16* Kpb  = (u16*)ws;  ws += (size_t)NB * NH * BHSTRIDE * 2; // 32 MB
  u16* Vtb  = (u16*)ws;  ws += (size_t)NB * NH * BHSTRIDE * 2; // 32 MB
  u16* Oab  = (u16*)ws;  ws += (size_t)NROWS * EMB * 2;        // 32 MB

  cvt_x_kernel<<<(NROWS * EMB) / (256 * 8), 256, 0, stream>>>(x, xb);

  dim3 tg(EMB / 32, EMB / 32, 4);
  transpose_cvt4_kernel<<<tg, 256, 0, stream>>>(
      Wq, Wk, Wv, Wo, Wt, Wt + (size_t)EMB * EMB, Wt + (size_t)2 * EMB * EMB, Wot);

  gemm8p_kernel<<<(NROWS / 256) * (3 * EMB / 256), 512, 0, stream>>>(
      xb, Wt, bq, bk, bv, nullptr, Qbuf, Kpb, Vtb, 3 * EMB, 0);

  attn_kernel<<<NB * NH * (S_LEN / QBLK), 256, 0, stream>>>(Qbuf, Kpb, Vtb, Oab);

  gemm8p_kernel<<<(NROWS / 256) * (EMB / 256), 512, 0, stream>>>(
      Oab, Wot, bo, bo, bo, d_out, nullptr, nullptr, nullptr, EMB, 1);
}

// Round 9
// 240.585 us; speedup vs baseline: 1.1570x; 1.0309x over previous
//
#include <hip/hip_runtime.h>
#include <hip/hip_bf16.h>
#include <type_traits>

typedef unsigned short u16;
typedef __attribute__((ext_vector_type(8))) short  s16x8;
typedef __attribute__((ext_vector_type(4))) short  s16x4;
typedef __attribute__((ext_vector_type(8))) __bf16 b16x8;
typedef __attribute__((ext_vector_type(4))) float  f32x4;

#define S_LEN 4096
#define NB    4
#define EMB   1024
#define NH    16
#define HD    64
#define NROWS (NB * S_LEN)   // 16384
#define KDIM  1024
#define BHSTRIDE (S_LEN * HD)   // 262144 u16 per (b,h) for Kp / Vt

static __device__ __forceinline__ u16 f2b(float f) {
  __hip_bfloat16 h = __float2bfloat16(f);
  return __builtin_bit_cast(u16, h);
}

// ---- MFMA shim ----
template <typename T, typename = void>
struct mfma_takes : std::false_type {};
template <typename T>
struct mfma_takes<T, std::void_t<decltype(__builtin_amdgcn_mfma_f32_16x16x32_bf16(
    std::declval<T>(), std::declval<T>(), std::declval<f32x4>(), 0, 0, 0))>> : std::true_type {};

template <typename AB>
static __device__ __forceinline__ f32x4 mfma_any(AB a, AB b, f32x4 c) {
  return __builtin_amdgcn_mfma_f32_16x16x32_bf16(a, b, c, 0, 0, 0);
}

template <typename S8 = s16x8, typename B8 = b16x8>
static __device__ __forceinline__ f32x4 MFMA_BF16(s16x8 a, s16x8 b, f32x4 c) {
  if constexpr (mfma_takes<S8>::value)
    return mfma_any<S8>(__builtin_bit_cast(S8, a), __builtin_bit_cast(S8, b), c);
  else
    return mfma_any<B8>(__builtin_bit_cast(B8, a), __builtin_bit_cast(B8, b), c);
}

static __device__ __forceinline__ void gld_lds16(const void* g, void* l) {
  __builtin_amdgcn_global_load_lds((const __attribute__((address_space(1))) void*)g,
                                   (__attribute__((address_space(3))) void*)l, 16, 0, 0);
}

// ---------------- fp32 -> bf16 conversion (x) ----------------
__global__ __launch_bounds__(256) void cvt_x_kernel(const float* __restrict__ in,
                                                    u16* __restrict__ out) {
  long i = ((long)blockIdx.x * 256 + threadIdx.x) * 8;
  float4 a = *(const float4*)(in + i);
  float4 b = *(const float4*)(in + i + 4);
  s16x8 o;
  o[0] = (short)f2b(a.x); o[1] = (short)f2b(a.y); o[2] = (short)f2b(a.z); o[3] = (short)f2b(a.w);
  o[4] = (short)f2b(b.x); o[5] = (short)f2b(b.y); o[6] = (short)f2b(b.z); o[7] = (short)f2b(b.w);
  *(s16x8*)(out + i) = o;
}

// ---------------- transpose + convert 4 x W, fused ----------------
__global__ __launch_bounds__(256) void transpose_cvt4_kernel(
    const float* __restrict__ W0, const float* __restrict__ W1,
    const float* __restrict__ W2, const float* __restrict__ W3,
    u16* __restrict__ D0, u16* __restrict__ D1, u16* __restrict__ D2, u16* __restrict__ D3) {
  __shared__ float tile[32][33];
  const float* W; u16* D;
  switch (blockIdx.z) {
    case 0:  W = W0; D = D0; break;
    case 1:  W = W1; D = D1; break;
    case 2:  W = W2; D = D2; break;
    default: W = W3; D = D3; break;
  }
  int n0 = blockIdx.x * 32, k0 = blockIdx.y * 32;
  int tx = threadIdx.x & 31, ty = threadIdx.x >> 5;
#pragma unroll
  for (int i = ty; i < 32; i += 8)
    tile[i][tx] = W[(long)(k0 + i) * EMB + n0 + tx];
  __syncthreads();
#pragma unroll
  for (int i = ty; i < 32; i += 8)
    D[(long)(n0 + i) * EMB + k0 + tx] = f2b(tile[tx][i]);
}

// ================= 256x256 8-phase GEMM (r3 choreography) =================
// vmcnt(8) at P2/P4/P6/P8 only ever waits on loads >= 2 phases old (ledger verified r3/r7).
#define SA_(p,k) (((p)*2+(k))*8192)
#define SB_(p,k) (32768 + ((p)*2+(k))*8192)

__global__ __launch_bounds__(512, 2) void gemm8p_kernel(
    const u16* __restrict__ A, const u16* __restrict__ Bt,
    const float* __restrict__ b0, const float* __restrict__ b1, const float* __restrict__ b2,
    void* __restrict__ Cp, u16* __restrict__ Qb, u16* __restrict__ Kp, u16* __restrict__ Vt,
    int N, int out_f32) {
  __shared__ __align__(16) u16 smem[65536];   // 128 KiB
  const int tid = threadIdx.x;
  const int w = tid >> 6, lane = tid & 63;
  const int wm = w >> 2, wn = w & 3;
  const int frow = lane & 15, fg = lane >> 4;

  const int nwg = gridDim.x;
  const int bid = ((int)blockIdx.x & 7) * (nwg >> 3) + ((int)blockIdx.x >> 3);
  const int nbn = N >> 8;
  const int bm = bid / nbn, bn = bid % nbn;

  int offA[8];
#pragma unroll
  for (int j = 0; j < 8; j++) {
    int row = wm * 128 + j * 16 + frow;
    offA[j] = row * 32 + ((fg ^ ((row ^ (row >> 2)) & 3)) << 3);
  }
  int offB[4];
#pragma unroll
  for (int j = 0; j < 4; j++) {
    int row = wn * 64 + j * 16 + frow;
    offB[j] = row * 32 + ((fg ^ ((row ^ (row >> 2)) & 3)) << 3);
  }
  int srow[2], soff[2];
#pragma unroll
  for (int L = 0; L < 2; L++) {
    int lin = L * 512 + tid;
    int r = lin >> 2;
    srow[L] = r;
    soff[L] = (((lin & 3) ^ ((r ^ (r >> 2)) & 3)) << 3);
  }
  const u16* Abase = A + (long)bm * 256 * KDIM;
  const u16* Bbase = Bt + (long)bn * 256 * KDIM;

  f32x4 acc[8][4];
#pragma unroll
  for (int m = 0; m < 8; m++)
#pragma unroll
    for (int n = 0; n < 4; n++) acc[m][n] = (f32x4)0.0f;

  auto STAGE = [&](const u16* gb, int kcol, int slot) {
#pragma unroll
    for (int L = 0; L < 2; L++)
      gld_lds16(gb + (long)srow[L] * KDIM + kcol + soff[L],
                &smem[slot + (L * 512 + w * 64) * 8]);
  };

  s16x8 af[4], bf[4];

  STAGE(Abase, 0,  SA_(0,0)); STAGE(Bbase, 0,  SB_(0,0));
  STAGE(Abase, 32, SA_(0,1)); STAGE(Bbase, 32, SB_(0,1));
  STAGE(Abase, 64, SA_(1,0)); STAGE(Bbase, 64, SB_(1,0));
  asm volatile("s_waitcnt vmcnt(8)" ::: "memory");
  asm volatile("s_barrier" ::: "memory");

#define PHASE(p, k, mh, RDB, GB, KCOL, SLOT, DOVM)                            \
  {                                                                           \
    if (RDB) {                                                                \
      _Pragma("unroll") for (int n = 0; n < 4; n++)                           \
        bf[n] = *(const s16x8*)&smem[SB_(p, k) + offB[n]];                    \
    }                                                                         \
    _Pragma("unroll") for (int m = 0; m < 4; m++)                             \
      af[m] = *(const s16x8*)&smem[SA_(p, k) + offA[(mh) * 4 + m]];           \
    STAGE(GB, KCOL, SLOT);                                                    \
    asm volatile("s_barrier" ::: "memory");                                   \
    asm volatile("s_waitcnt lgkmcnt(0)" ::: "memory");                        \
    __builtin_amdgcn_sched_barrier(0);                                        \
    __builtin_amdgcn_s_setprio(1);                                            \
    _Pragma("unroll") for (int m = 0; m < 4; m++)                             \
      _Pragma("unroll") for (int n = 0; n < 4; n++)                           \
        acc[(mh) * 4 + m][n] = MFMA_BF16(af[m], bf[n], acc[(mh) * 4 + m][n]); \
    __builtin_amdgcn_s_setprio(0);                                            \
    if (DOVM) asm volatile("s_waitcnt vmcnt(8)" ::: "memory");                \
    asm volatile("s_barrier" ::: "memory");                                   \
  }

#pragma unroll 1
  for (int i = 0; i < 8; i++) {
    const int t = 2 * i;
    const int k1 = ((t + 1) & 15) * 64;
    const int k2 = ((t + 2) & 15) * 64;   // wraps harmlessly on last iter (data unused)
    const int k3 = ((t + 3) & 15) * 64;
    PHASE(0, 0, 0, 1, Abase, k1 + 32, SA_(1, 1), 0)
    PHASE(0, 0, 1, 0, Bbase, k1 + 32, SB_(1, 1), 1)
    PHASE(0, 1, 0, 1, Abase, k2,      SA_(0, 0), 0)
    PHASE(0, 1, 1, 0, Bbase, k2,      SB_(0, 0), 1)
    PHASE(1, 0, 0, 1, Abase, k2 + 32, SA_(0, 1), 0)
    PHASE(1, 0, 1, 0, Bbase, k2 + 32, SB_(0, 1), 1)
    PHASE(1, 1, 0, 1, Abase, k3,      SA_(1, 0), 0)
    PHASE(1, 1, 1, 0, Bbase, k3,      SB_(1, 0), 1)
  }
#undef PHASE

  asm volatile("s_waitcnt vmcnt(0) lgkmcnt(0)" ::: "memory");
  asm volatile("s_barrier" ::: "memory");

  const int Mbase = bm * 256 + wm * 128;

  if (!out_f32) {
    const int g = bn * 256 + wn * 64;      // wave's global col slab = one head
    const int part = g >> 10;              // 0=Q 1=K 2=V
    const int head = (g & 1023) >> 6;
    const float* bias = (part == 0) ? b0 : ((part == 1) ? b1 : b2);
    float bv[4];
#pragma unroll
    for (int n = 0; n < 4; n++) bv[n] = bias[(g & 1023) + n * 16 + frow];

    if (part == 2) {
      // ---- V: per-wave [64][40]-u16 transpose bounce -> full-sector coalesced stores.
      // Writes: C-layout scalars; reads: s16x8 along s (16B-aligned via pitch 80B);
      // stores: 16 d-rows x 64B full sectors per instruction (no partial-sector RMW).
      u16* vbuf = &smem[w * 2560];         // [64][40] u16 = 5 KB/wave
      const int batch = Mbase >> 12;
      u16* dstb = Vt + ((long)(batch * 16 + head)) * BHSTRIDE;
#pragma unroll
      for (int mf2 = 0; mf2 < 4; mf2++) {
        const int s0 = (Mbase & 4095) + mf2 * 32;
#pragma unroll
        for (int half = 0; half < 2; half++) {
          const int mf = mf2 * 2 + half;
#pragma unroll
          for (int n = 0; n < 4; n++) {
            const int d = n * 16 + frow;
#pragma unroll
            for (int r = 0; r < 4; r++)
              vbuf[d * 40 + half * 16 + 4 * fg + r] = f2b(acc[mf][n][r] + bv[n]);
          }
        }
        asm volatile("s_waitcnt lgkmcnt(0)" ::: "memory");
        __builtin_amdgcn_sched_barrier(0);
#pragma unroll
        for (int i = 0; i < 4; i++) {
          const int d = i * 16 + (lane >> 2);
          const int sl = lane & 3;
          s16x8 v = *(const s16x8*)&vbuf[d * 40 + sl * 8];
          *(s16x8*)(dstb + (long)d * S_LEN + s0 + sl * 8) = v;
        }
        asm volatile("s_waitcnt lgkmcnt(0)" ::: "memory");
        __builtin_amdgcn_sched_barrier(0);
      }
    } else {
      // ---- Q/K: swizzled wave-private bounce -> coalesced b128 stores
      u16* buf = &smem[w * 2048];            // [32][64] swizzled, 4KB/wave
#pragma unroll
      for (int mf2 = 0; mf2 < 4; mf2++) {
#pragma unroll
        for (int half = 0; half < 2; half++) {
          const int mf = mf2 * 2 + half;
#pragma unroll
          for (int n = 0; n < 4; n++)
#pragma unroll
            for (int r = 0; r < 4; r++) {
              int row32 = half * 16 + 4 * fg + r;
              int col = n * 16 + frow;
              buf[row32 * 64 + (((col >> 3) ^ (row32 & 7)) << 3) + (col & 7)] =
                  f2b(acc[mf][n][r] + bv[n]);
            }
        }
        asm volatile("s_waitcnt lgkmcnt(0)" ::: "memory");
        __builtin_amdgcn_sched_barrier(0);
        const int s0 = Mbase + mf2 * 32;
#pragma unroll
        for (int i = 0; i < 4; i++) {
          int flat = lane + 64 * i;
          int row32 = flat >> 3, ch = flat & 7;
          s16x8 v = *(const s16x8*)&buf[row32 * 64 + ((ch ^ (row32 & 7)) << 3)];
          int s = s0 + row32;
          u16* dst = (part == 0)
              ? (Qb + (long)s * 1024 + head * 64 + ch * 8)
              : (Kp + ((long)(s >> 12) * 16 + head) * BHSTRIDE + (long)(s & 4095) * 64 + ch * 8);
          *(s16x8*)dst = v;
        }
        asm volatile("s_waitcnt lgkmcnt(0)" ::: "memory");
        __builtin_amdgcn_sched_barrier(0);
      }
    }
  } else {
    // ---- f32 writer (gemm2): swizzled pitch-64 f32 bounce ----
    float* fbuf = (float*)&smem[w * 2048];   // [16][64] f32, 4KB/wave
    const long crow0 = (long)Mbase * N + bn * 256 + wn * 64;
#pragma unroll
    for (int mf = 0; mf < 8; mf++) {
#pragma unroll
      for (int n = 0; n < 4; n++) {
        float bvv = b0[(bn * 256 + wn * 64 + n * 16 + frow) & 1023];
#pragma unroll
        for (int r = 0; r < 4; r++) {
          int row = 4 * fg + r;
          int o = 4 * n + (frow >> 2);
          fbuf[row * 64 + ((o ^ (row & 7)) << 2) + (frow & 3)] = acc[mf][n][r] + bvv;
        }
      }
      asm volatile("s_waitcnt lgkmcnt(0)" ::: "memory");
      __builtin_amdgcn_sched_barrier(0);
#pragma unroll
      for (int i = 0; i < 4; i++) {
        int flat = lane + 64 * i;
        int row = flat >> 4, oct = lane & 15;
        float4 v = *(const float4*)&fbuf[row * 64 + ((oct ^ (row & 7)) << 2)];
        *(float4*)((float*)Cp + crow0 + (long)(mf * 16 + row) * N + oct * 4) = v;
      }
      asm volatile("s_waitcnt lgkmcnt(0)" ::: "memory");
      __builtin_amdgcn_sched_barrier(0);
    }
  }
}

// ---------------- local attention (DMA staging, double-buffered, defer-max) ----------------
// Interior tiles (-97 <= kvb-qw0 <= 65): every (q,kv) pair of the wave is inside the
// window -> skip the mask entirely (wave-uniform branch). Boundary kv-range is always
// in-bounds by tile clamping, so mask == window check only.
#define QBLK 128

__global__ __launch_bounds__(256) void attn_kernel(const u16* __restrict__ Qb,
                                                   const u16* __restrict__ Kp,
                                                   const u16* __restrict__ Vt,
                                                   u16* __restrict__ Oa) {
  __shared__ __align__(16) u16 smem[16384];   // lK[2][64][64] + lV[2][64][64] = 32KB

  const int tid = threadIdx.x;
  const int w = tid >> 6, lane = tid & 63;
  const int frow = lane & 15, fg = lane >> 4;

  const int nq = S_LEN / QBLK;             // 32
  int bid = (int)blockIdx.x;
  bid = (bid & 7) * ((NB * NH * nq) >> 3) + (bid >> 3);   // XCD swizzle
  const int b = bid / (NH * nq);
  const int rem = bid % (NH * nq);
  const int h = rem / nq;
  const int qt = rem % nq;
  const int q0 = qt * QBLK;
  const int qw0 = q0 + 32 * w;

  const u16* Kpb = Kp + (long)(b * NH + h) * BHSTRIDE;
  const u16* Vtb = Vt + (long)(b * NH + h) * BHSTRIDE;

  s16x8 qf[2][2];
#pragma unroll
  for (int m = 0; m < 2; m++)
#pragma unroll
    for (int kk = 0; kk < 2; kk++)
      qf[m][kk] = *(const s16x8*)(Qb + (long)(b * S_LEN + qw0 + 16 * m + frow) * 1024 +
                                  h * 64 + kk * 32 + 8 * fg);

  f32x4 acc[2][4];
#pragma unroll
  for (int m = 0; m < 2; m++)
#pragma unroll
    for (int n = 0; n < 4; n++) acc[m][n] = (f32x4)0.0f;
  float mrow[2] = {-1e30f, -1e30f};
  float lrow[2] = {0.f, 0.f};

  const int r8 = lane >> 3;
  const int cs = ((lane & 7) ^ r8) << 3;     // swizzled source chunk (u16 units)

  auto STAGE = [&](int kvb, int bufi) {
#pragma unroll
    for (int pass = 0; pass < 2; pass++) {
      int rbase = pass * 32 + w * 8;
      gld_lds16(Kpb + (long)(kvb + rbase + r8) * 64 + cs, &smem[bufi * 4096 + rbase * 64]);
      gld_lds16(Vtb + (long)(rbase + r8) * S_LEN + kvb + cs, &smem[8192 + bufi * 4096 + rbase * 64]);
    }
  };

  const int tlo = (q0 == 0) ? 2 : 0;
  const int thi = (q0 == S_LEN - QBLK) ? 3 : 5;

  STAGE(q0 - 128 + 64 * tlo, 0);

#pragma unroll 1
  for (int t = tlo; t <= thi; t++) {
    const int cur = (t - tlo) & 1;
    const int kvb = q0 - 128 + 64 * t;
    if (t < thi) {
      STAGE(kvb + 64, cur ^ 1);
      asm volatile("s_waitcnt vmcnt(4)" ::: "memory");
    } else {
      asm volatile("s_waitcnt vmcnt(0)" ::: "memory");
    }
    asm volatile("s_barrier" ::: "memory");

    const bool active = (kvb + 63 >= qw0 - 128) && (kvb <= qw0 + 159);
    if (active) {
      const u16* lK = &smem[cur * 4096];
      const u16* lV = &smem[8192 + cur * 4096];
      const int delta = kvb - qw0;
      const bool interior = (delta >= -97) && (delta <= 65);
      // QK^T (swapped): sfr[m][n][r] = S[q = qw0+16m+frow][kv = kvb + 16n + 4fg + r]
      f32x4 sfr[2][4];
#pragma unroll
      for (int m = 0; m < 2; m++)
#pragma unroll
        for (int n = 0; n < 4; n++) sfr[m][n] = (f32x4)0.0f;
#pragma unroll
      for (int kk = 0; kk < 2; kk++) {
        s16x8 kb[4];
#pragma unroll
        for (int n = 0; n < 4; n++)
          kb[n] = *(const s16x8*)&lK[(16 * n + frow) * 64 + (((fg + 4 * kk) ^ (frow & 7)) << 3)];
#pragma unroll
        for (int m = 0; m < 2; m++)
#pragma unroll
          for (int n = 0; n < 4; n++)
            sfr[m][n] = MFMA_BF16(kb[n], qf[m][kk], sfr[m][n]);
      }
      // ---- softmax with defer-max (T13) ----
#pragma unroll
      for (int m = 0; m < 2; m++) {
        float tmax = -1e30f;
        if (interior) {
#pragma unroll
          for (int n = 0; n < 4; n++)
#pragma unroll
            for (int r = 0; r < 4; r++) {
              float xv = sfr[m][n][r] * 0.125f;
              sfr[m][n][r] = xv;
              tmax = fmaxf(tmax, xv);
            }
        } else {
          const int dbase = kvb - (qw0 + 16 * m + frow) + 128 + 4 * fg;  // + 16n + r
#pragma unroll
          for (int n = 0; n < 4; n++)
#pragma unroll
            for (int r = 0; r < 4; r++) {
              bool valid = (unsigned)(dbase + 16 * n + r) <= 256u;
              float xv = valid ? sfr[m][n][r] * 0.125f : -1e30f;
              sfr[m][n][r] = xv;
              tmax = fmaxf(tmax, xv);
            }
        }
        tmax = fmaxf(tmax, __shfl_xor(tmax, 16));
        tmax = fmaxf(tmax, __shfl_xor(tmax, 32));
        if (!__all(tmax - mrow[m] <= 8.0f)) {
          float mnew = fmaxf(mrow[m], tmax);
          float al = __expf(mrow[m] - mnew);
          mrow[m] = mnew;
          lrow[m] *= al;
          float a4[4];
#pragma unroll
          for (int r = 0; r < 4; r++) a4[r] = __shfl(al, 20 * fg + r);
#pragma unroll
          for (int nd = 0; nd < 4; nd++)
#pragma unroll
            for (int r = 0; r < 4; r++) acc[m][nd][r] *= a4[r];
        }
        float ps = 0.f;
#pragma unroll
        for (int n = 0; n < 4; n++)
#pragma unroll
          for (int r = 0; r < 4; r++) {
            float e = __expf(sfr[m][n][r] - mrow[m]);   // masked: exp(-huge) -> 0
            sfr[m][n][r] = e;
            ps += e;
          }
        ps += __shfl_xor(ps, 16);
        ps += __shfl_xor(ps, 32);
        lrow[m] += ps;
      }
      // pack P A-fragments (k-permutation pi: k=fg*8+j <-> kv=16*(2kt+(j>>2))+4fg+(j&3))
      s16x8 pa[2][2];
#pragma unroll
      for (int m = 0; m < 2; m++)
#pragma unroll
        for (int kt = 0; kt < 2; kt++)
#pragma unroll
          for (int j = 0; j < 8; j++)
            pa[m][kt][j] = (short)f2b(sfr[m][2 * kt + (j >> 2)][j & 3]);
      // PV: V-fragments read once, shared by both m
#pragma unroll
      for (int kt = 0; kt < 2; kt++)
#pragma unroll
        for (int nd = 0; nd < 4; nd++) {
          const int d = 16 * nd + frow;
          const int key = frow & 7;
          const int olo = (4 * kt + (fg >> 1)) ^ key;
          const int ohi = (4 * kt + 2 + (fg >> 1)) ^ key;
          s16x4 lo = *(const s16x4*)&lV[d * 64 + olo * 8 + (fg & 1) * 4];
          s16x4 hi = *(const s16x4*)&lV[d * 64 + ohi * 8 + (fg & 1) * 4];
          s16x8 vb;
          vb[0] = lo[0]; vb[1] = lo[1]; vb[2] = lo[2]; vb[3] = lo[3];
          vb[4] = hi[0]; vb[5] = hi[1]; vb[6] = hi[2]; vb[7] = hi[3];
#pragma unroll
          for (int m = 0; m < 2; m++)
            acc[m][nd] = MFMA_BF16(pa[m][kt], vb, acc[m][nd]);
        }
    }
    asm volatile("s_barrier" ::: "memory");
  }

  float i4[2][4];
#pragma unroll
  for (int m = 0; m < 2; m++) {
    float inv = 1.0f / lrow[m];
#pragma unroll
    for (int r = 0; r < 4; r++) i4[m][r] = __shfl(inv, 20 * fg + r);
  }
  u16* bb = &smem[w * 2048];   // [32][64] swizzled
#pragma unroll
  for (int m = 0; m < 2; m++)
#pragma unroll
    for (int nd = 0; nd < 4; nd++)
#pragma unroll
      for (int r = 0; r < 4; r++) {
        int row32 = 16 * m + 4 * fg + r;
        int col = 16 * nd + frow;
        bb[row32 * 64 + (((col >> 3) ^ (row32 & 7)) << 3) + (col & 7)] =
            f2b(acc[m][nd][r] * i4[m][r]);
      }
  asm volatile("s_waitcnt lgkmcnt(0)" ::: "memory");
  __builtin_amdgcn_sched_barrier(0);
  u16* Ob = Oa + ((long)(b * S_LEN + qw0)) * EMB + h * HD;
#pragma unroll
  for (int i = 0; i < 4; i++) {
    int flat = lane + 64 * i;
    int row32 = flat >> 3, ch = flat & 7;
    s16x8 v = *(const s16x8*)&bb[row32 * 64 + ((ch ^ (row32 & 7)) << 3)];
    *(s16x8*)(Ob + (long)row32 * EMB + ch * 8) = v;
  }
}

extern "C" void kernel_launch(void* const* d_in, const int* in_sizes, int n_in,
                              void* d_out, int out_size, void* d_ws, size_t ws_size,
                              hipStream_t stream) {
  const float* x  = (const float*)d_in[0];
  const float* Wq = (const float*)d_in[1];
  const float* bq = (const float*)d_in[2];
  const float* Wk = (const float*)d_in[3];
  const float* bk = (const float*)d_in[4];
  const float* Wv = (const float*)d_in[5];
  const float* bv = (const float*)d_in[6];
  const float* Wo = (const float*)d_in[7];
  const float* bo = (const float*)d_in[8];

  char* ws = (char*)d_ws;
  u16* xb   = (u16*)ws;  ws += (size_t)NROWS * EMB * 2;        // 32 MB
  u16* Wt   = (u16*)ws;  ws += (size_t)3 * EMB * EMB * 2;      // 6 MB
  u16* Wot  = (u16*)ws;  ws += (size_t)EMB * EMB * 2;          // 2 MB
  u16* Qbuf = (u16*)ws;  ws += (size_t)NROWS * EMB * 2;        // 32 MB
  u16* Kpb  = (u16*)ws;  ws += (size_t)NB * NH * BHSTRIDE * 2; // 32 MB
  u16* Vtb  = (u16*)ws;  ws += (size_t)NB * NH * BHSTRIDE * 2; // 32 MB
  u16* Oab  = (u16*)ws;  ws += (size_t)NROWS * EMB * 2;        // 32 MB

  cvt_x_kernel<<<(NROWS * EMB) / (256 * 8), 256, 0, stream>>>(x, xb);

  dim3 tg(EMB / 32, EMB / 32, 4);
  transpose_cvt4_kernel<<<tg, 256, 0, stream>>>(
      Wq, Wk, Wv, Wo, Wt, Wt + (size_t)EMB * EMB, Wt + (size_t)2 * EMB * EMB, Wot);

  gemm8p_kernel<<<(NROWS / 256) * (3 * EMB / 256), 512, 0, stream>>>(
      xb, Wt, bq, bk, bv, nullptr, Qbuf, Kpb, Vtb, 3 * EMB, 0);

  attn_kernel<<<NB * NH * (S_LEN / QBLK), 256, 0, stream>>>(Qbuf, Kpb, Vtb, Oab);

  gemm8p_kernel<<<(NROWS / 256) * (EMB / 256), 512, 0, stream>>>(
      Oab, Wot, bo, bo, bo, d_out, nullptr, nullptr, nullptr, EMB, 1);
}